// Round 14
// baseline (445.699 us; speedup 1.0000x reference)
//
#include <hip/hip_runtime.h>
#include <math.h>

// Problem constants
#define BB   4
#define LL   4096          // H*W
#define L2T  8192          // 2*L (modality-interleaved sequence)
#define DM   96            // D_MODEL
#define CI   192           // D_INNER
#define KD   4             // K directions
#define NN   16            // D_STATE
#define RR   6             // DT_RANK
#define BKT  16            // B*K
#define SS   128           // scan segments
#define TT   64            // steps per segment = L2T/SS
#define DBLS 40            // padded row stride for x_dbl (38 -> 40 for float4)

// Workspace layout (float offsets) — identical to R9/R11/R13 (proven passing incl. post-timing)
#define OFF_XPRE1 0
#define OFF_XPRE2 3145728
#define OFF_Z1    6291456
#define OFF_Z2    9437184
#define OFF_X1C   12582912
#define OFF_X2C   15728640
#define OFF_DBL   18874368   // BKT*L2T*40 = 5242880
#define OFF_MERG  24117248   // B*L*2*CI = 6291456 == SS*BKT*CI*NN (hend fits exactly)
#define OFF_DSUM  30408704   // SS*BKT*CI = 393216

// ---------------- in_proj: LDS-tiled GEMM. M=16384, N=384 (4 tiles of 96), K=96 ----------------
__global__ __launch_bounds__(256)
void k_inproj(const float* __restrict__ rgb, const float* __restrict__ tin,
              const float* __restrict__ w1, const float* __restrict__ w2,
              float* __restrict__ xp1, float* __restrict__ xp2,
              float* __restrict__ zz1, float* __restrict__ zz2) {
  int mb = blockIdx.x;     // row tile
  int nb = blockIdx.y;     // col tile (0..3)
  int m  = blockIdx.z;     // modality
  const float* in = m ? tin : rgb;
  const float* w  = (m ? w2 : w1) + nb * 96 * DM;
  __shared__ float As[64][100];
  __shared__ float Ws[96][98];
  int t = threadIdx.x;
  const float4* asrc = (const float4*)(in + (size_t)mb * 64 * DM);
  for (int i = t; i < 1536; i += 256) {
    int r = i / 24, kk = (i % 24) * 4;
    *(float4*)&As[r][kk] = asrc[i];
  }
  const float2* wsrc = (const float2*)w;
  for (int i = t; i < 4608; i += 256) {
    int r = i / 48, kk = (i % 48) * 2;
    *(float2*)&Ws[r][kk] = wsrc[i];
  }
  __syncthreads();
  int tc = t & 15, tr = t >> 4;
  float acc[4][6] = {};
  for (int k = 0; k < 96; k += 2) {
    float2 a[4], b[6];
#pragma unroll
    for (int i = 0; i < 4; i++) a[i] = *(const float2*)&As[tr * 4 + i][k];
#pragma unroll
    for (int j = 0; j < 6; j++) b[j] = *(const float2*)&Ws[tc * 6 + j][k];
#pragma unroll
    for (int i = 0; i < 4; i++)
#pragma unroll
      for (int j = 0; j < 6; j++) {
        acc[i][j] = fmaf(a[i].x, b[j].x, acc[i][j]);
        acc[i][j] = fmaf(a[i].y, b[j].y, acc[i][j]);
      }
  }
  float* dst = (nb < 2) ? (m ? xp2 : xp1) : (m ? zz2 : zz1);
  int colbase = (nb & 1) * 96 + tc * 6;
#pragma unroll
  for (int i = 0; i < 4; i++) {
    size_t bl = (size_t)mb * 64 + tr * 4 + i;
#pragma unroll
    for (int j = 0; j < 6; j++)
      dst[bl * CI + colbase + j] = acc[i][j];
  }
}

// ---------------- depthwise 3x3 conv (SAME, zero pad) + bias + SiLU ----------------
__global__ __launch_bounds__(256)
void k_conv(const float* __restrict__ xp1, const float* __restrict__ xp2,
            const float* __restrict__ c1w, const float* __restrict__ c1b,
            const float* __restrict__ c2w, const float* __restrict__ c2b,
            float* __restrict__ o1, float* __restrict__ o2) {
  int m = blockIdx.y;
  const float* in = m ? xp2 : xp1;
  const float* cw = m ? c2w : c1w;
  const float* cb = m ? c2b : c1b;
  float* out = m ? o2 : o1;
  int idx = blockIdx.x * 256 + threadIdx.x;
  int c = idx % CI;
  int bl = idx / CI;
  int b = bl / LL, l = bl % LL;
  int hh = l >> 6, ww = l & 63;
  float a = cb[c];
#pragma unroll
  for (int di = 0; di < 3; di++) {
    int h2 = hh + di - 1;
    if ((unsigned)h2 >= 64u) continue;
#pragma unroll
    for (int dj = 0; dj < 3; dj++) {
      int w2 = ww + dj - 1;
      if ((unsigned)w2 >= 64u) continue;
      a = fmaf(in[(b * LL + h2 * 64 + w2) * CI + c], cw[c * 9 + di * 3 + dj], a);
    }
  }
  out[idx] = a / (1.f + __expf(-a));
}

// ---------------- x_dbl projection, DIRECTION-PAIRED: block computes k and k+2 from one x tile ----
// grid (128, 8): pk = b*2 + kp; kp=0 -> dirs {0,2}, kp=1 -> dirs {1,3}.
// As row r <-> (l = pt*32 + (r>>1), m = r&1), gathered at sp = kp ? transpose(l) : l.
// k_lo output row: pt*64 + r. k_hi (=k_lo+2) output row: L2T - pt*64 - 2*(r>>1) - 2 + (r&1).
__global__ __launch_bounds__(256)
void k_dbl(const float* __restrict__ x1c, const float* __restrict__ x2c,
           const float* __restrict__ wx, float* __restrict__ dbl) {
  int pt = blockIdx.x;
  int pk = blockIdx.y;
  int b = pk >> 1, kp = pk & 1;
  int klo = kp, khi = kp + 2;
  __shared__ float As[64][100];
  __shared__ float Ws[2][40][100];
  int t = threadIdx.x;
  int tc = t & 7, tr = t >> 3;
  float acc[2][2][5] = {};
  for (int kc = 0; kc < 2; kc++) {
    if (kc) __syncthreads();
    for (int i = t; i < 1536; i += 256) {
      int r = i / 24, kk = (i % 24) * 4;
      int l = pt * 32 + (r >> 1);
      int mm = r & 1;
      int sp = kp ? (((l & 63) << 6) | (l >> 6)) : l;
      const float* src = (mm ? x2c : x1c) + ((size_t)(b * LL + sp)) * CI + kc * 96;
      *(float4*)&As[r][kk] = *(const float4*)(src + kk);
    }
    for (int i = t; i < 1920; i += 256) {
      int d = i / 960;
      int r = (i % 960) / 24, kk = (i % 24) * 4;
      int kd = d ? khi : klo;
      float4 v;
      if (r < 38) v = *(const float4*)&wx[(size_t)(kd * 38 + r) * CI + kc * 96 + kk];
      else        v = float4{0.f, 0.f, 0.f, 0.f};
      *(float4*)&Ws[d][r][kk] = v;
    }
    __syncthreads();
    for (int kk2 = 0; kk2 < 96; kk2 += 2) {
      float2 a[2], bv0[5], bv1[5];
#pragma unroll
      for (int i = 0; i < 2; i++) a[i] = *(const float2*)&As[tr * 2 + i][kk2];
#pragma unroll
      for (int j = 0; j < 5; j++) {
        bv0[j] = *(const float2*)&Ws[0][tc * 5 + j][kk2];
        bv1[j] = *(const float2*)&Ws[1][tc * 5 + j][kk2];
      }
#pragma unroll
      for (int i = 0; i < 2; i++)
#pragma unroll
        for (int j = 0; j < 5; j++) {
          acc[0][i][j] = fmaf(a[i].x, bv0[j].x, acc[0][i][j]);
          acc[0][i][j] = fmaf(a[i].y, bv0[j].y, acc[0][i][j]);
          acc[1][i][j] = fmaf(a[i].x, bv1[j].x, acc[1][i][j]);
          acc[1][i][j] = fmaf(a[i].y, bv1[j].y, acc[1][i][j]);
        }
    }
  }
#pragma unroll
  for (int i = 0; i < 2; i++) {
    int r = tr * 2 + i;
    size_t rowlo = (size_t)(b * 4 + klo) * L2T + pt * 64 + r;
    int l2p = L2T - pt * 64 - 2 * (r >> 1) - 2 + (r & 1);
    size_t rowhi = (size_t)(b * 4 + khi) * L2T + l2p;
#pragma unroll
    for (int j = 0; j < 5; j++) {
      int cc = tc * 5 + j;
      if (cc < 38) {
        dbl[rowlo * DBLS + cc] = acc[0][i][j];
        dbl[rowhi * DBLS + cc] = acc[1][i][j];
      }
    }
  }
}

// ---------------- segmented selective scan: 192-thread blocks (UNCHANGED from R13/R11) ----------------
template<int PASS>
__global__ __launch_bounds__(192)
void k_scan(const float* __restrict__ x1c, const float* __restrict__ x2c,
            const float* __restrict__ dbl,
            const float* __restrict__ dtw, const float* __restrict__ dtb,
            const float* __restrict__ alogs, const float* __restrict__ dsv,
            float* __restrict__ hend, float* __restrict__ dsum,
            const float* __restrict__ hin, float* __restrict__ merged) {
  int bid = blockIdx.x;          // SS*BKT
  int s  = bid & (SS - 1);
  int bk = bid >> 7;             // 0..15
  int b = bk >> 2, kdir = bk & 3;
  int c = threadIdx.x;           // 0..191 (wave w covers c in [w*64, w*64+64))
  int kc = kdir * CI + c;

  float w2r0 = dtw[kc * RR + 0], w2r1 = dtw[kc * RR + 1], w2r2 = dtw[kc * RR + 2];
  float w2r3 = dtw[kc * RR + 3], w2r4 = dtw[kc * RR + 4], w2r5 = dtw[kc * RR + 5];
  float bias = dtb[kc];
  float Dv   = (PASS == 2) ? dsv[kc] : 0.f;
  float Areg[NN];
#pragma unroll
  for (int n = 0; n < NN; n++) Areg[n] = -__expf(alogs[kc * NN + n]);
  float A1 = Areg[0];
  int ok = 1;
#pragma unroll
  for (int n = 1; n < NN; n++) {
    float want = A1 * (float)(n + 1);
    if (!(fabsf(Areg[n] - want) <= fabsf(want) * 1e-3f + 1e-6f)) ok = 0;
  }
  const bool structured = (__all(ok) != 0);   // A[n] = (n+1)*A1 -> dA[n] = r^(n+1)

  float h[NN];
  if (PASS == 2) {
    int base = ((s * BKT + bk) * CI + c) * NN;
#pragma unroll
    for (int n = 0; n < NN; n++) h[n] = hin[base + n];
  } else {
#pragma unroll
    for (int n = 0; n < NN; n++) h[n] = 0.f;
  }
  float dacc = 0.f;

  const float4* dp4 = (const float4*)(dbl + (size_t)(bk * L2T + s * TT) * DBLS);  // block-uniform
  const float* u1b = x1c + (size_t)b * LL * CI + c;
  const float* u2b = x2c + (size_t)b * LL * CI + c;

  auto spmap = [&](int l) -> int {
    int lt = (kdir >= 2) ? (LL - 1 - l) : l;
    return (kdir & 1) ? (((lt & 63) << 6) | (lt >> 6)) : lt;
  };

  auto loadrow = [&](float4* Q, int t) {
    const float4* r4 = dp4 + t * 10;
    Q[0] = r4[0]; Q[1] = r4[1]; Q[2] = r4[2];
    Q[3] = r4[3]; Q[4] = r4[4]; Q[5] = r4[5];
    if (PASS == 2) { Q[6] = r4[6]; Q[7] = r4[7]; Q[8] = r4[8]; Q[9] = r4[9]; }
  };

#define DG(Q, i) ((i & 3) == 0 ? Q[(i) >> 2].x : (i & 3) == 1 ? Q[(i) >> 2].y : (i & 3) == 2 ? Q[(i) >> 2].z : Q[(i) >> 2].w)

  auto step = [&](const float4* Q, float u, float& y) {
    float x = bias;
    x = fmaf(DG(Q, 0), w2r0, x); x = fmaf(DG(Q, 1), w2r1, x); x = fmaf(DG(Q, 2), w2r2, x);
    x = fmaf(DG(Q, 3), w2r3, x); x = fmaf(DG(Q, 4), w2r4, x); x = fmaf(DG(Q, 5), w2r5, x);
    float delta = (x > 15.f) ? x : __logf(1.f + __expf(x));
    float du = delta * u;
    float y0 = 0.f, y1 = 0.f, y2 = 0.f, y3 = 0.f;
    if (structured) {
      float r  = __expf(delta * A1);
      float r2 = r * r, r3 = r2 * r, r4 = r2 * r2;
      float r6 = r4 * r2, r8 = r4 * r4;
      float pw[NN];
      pw[0] = r;       pw[1] = r2;      pw[2] = r3;      pw[3] = r4;
      pw[4] = r4 * r;  pw[5] = r6;      pw[6] = r4 * r3; pw[7] = r8;
      pw[8] = r8 * r;  pw[9] = r8 * r2; pw[10] = r8 * r3; pw[11] = r8 * r4;
      pw[12] = r8 * pw[4]; pw[13] = r8 * r6; pw[14] = r8 * pw[6]; pw[15] = r8 * r8;
#pragma unroll
      for (int n = 0; n < NN; n++) {
        h[n] = fmaf(h[n], pw[n], du * DG(Q, 6 + n));
        if (PASS == 2) {
          float* yp = (n & 2) ? ((n & 1) ? &y3 : &y2) : ((n & 1) ? &y1 : &y0);
          *yp = fmaf(h[n], DG(Q, 22 + n), *yp);
        }
      }
    } else {
#pragma unroll
      for (int n = 0; n < NN; n++) {
        float dA = __expf(delta * Areg[n]);
        h[n] = fmaf(h[n], dA, du * DG(Q, 6 + n));
        if (PASS == 2) {
          float* yp = (n & 2) ? ((n & 1) ? &y3 : &y2) : ((n & 1) ? &y1 : &y0);
          *yp = fmaf(h[n], DG(Q, 22 + n), *yp);
        }
      }
    }
    if (PASS == 1) dacc += delta;
    else y = fmaf(u, Dv, (y0 + y1) + (y2 + y3));
  };

  const int NP = TT / 2;         // pairs
  int l0 = (s * TT) >> 1;
  float4 qA[10], qB[10];
  int spC = spmap(l0);
  float u1C = u1b[(size_t)spC * CI];
  float u2C = u2b[(size_t)spC * CI];
  int spN = spmap(l0 + 1);
  float u1N = u1b[(size_t)spN * CI];
  float u2N = u2b[(size_t)spN * CI];
  int spN2 = spmap(l0 + 2);
  float u1N2 = u1b[(size_t)spN2 * CI];
  float u2N2 = u2b[(size_t)spN2 * CI];
  loadrow(qA, 0);
#pragma unroll 1
  for (int t = 0; t < TT; t += 2) {
    int p = t >> 1;
    loadrow(qB, t + 1);
    int spN3 = 0; float u1N3 = 0.f, u2N3 = 0.f;
    if (p + 3 < NP) {
      spN3 = spmap(l0 + p + 3);
      u1N3 = u1b[(size_t)spN3 * CI];
      u2N3 = u2b[(size_t)spN3 * CI];
    }
    float ya, yb;
    step(qA, u1C, ya);
    if (t + 2 < TT) loadrow(qA, t + 2);
    step(qB, u2C, yb);
    if (PASS == 2) {
      float* mrow = merged + (size_t)(b * LL + spC) * (2 * CI) + c;
      atomicAdd(mrow, ya);
      atomicAdd(mrow + CI, yb);
    }
    spC = spN;  u1C = u1N;  u2C = u2N;
    spN = spN2; u1N = u1N2; u2N = u2N2;
    spN2 = spN3; u1N2 = u1N3; u2N2 = u2N3;
  }
#undef DG

  if (PASS == 1) {
    int base = ((s * BKT + bk) * CI + c) * NN;
#pragma unroll
    for (int n = 0; n < NN; n++) hend[base + n] = h[n];
    dsum[(s * BKT + bk) * CI + c] = dacc;
  }
}

// ---------------- propagate segment initial states (two-buffer, 2-deep prefetch) ----------------
__global__ __launch_bounds__(256)
void k_prop(const float* __restrict__ hend, const float* __restrict__ dsum,
            const float* __restrict__ alogs, float* __restrict__ hin) {
  int idx = blockIdx.x * 256 + threadIdx.x;   // BKT*CI*NN = 49152
  int n = idx & 15;
  int rest = idx >> 4;
  int c = rest % CI;
  int bk = rest / CI;
  int k = bk & 3;
  float A = -__expf(alogs[(k * CI + c) * NN + n]);
  float h = 0.f;
  int cell0 = bk * CI + c;                    // cell(s) = s*BKT*CI + cell0
  float heC = hend[(size_t)cell0 * NN + n];
  float dsC = dsum[cell0];
#pragma unroll 1
  for (int s = 0; s < SS; s++) {
    float heN = 0.f, dsN = 0.f;
    if (s + 1 < SS) {
      int cellN = (s + 1) * BKT * CI + cell0;
      heN = hend[(size_t)cellN * NN + n];
      dsN = dsum[cellN];
    }
    int cell = s * BKT * CI + cell0;
    hin[(size_t)cell * NN + n] = h;
    h = h * __expf(A * dsC) + heC;
    heC = heN; dsC = dsN;
  }
}

// ---------------- LayerNorm over CI + SiLU(z) gate: wave-per-row, 8 rows/wave ----------------
__global__ __launch_bounds__(256)
void k_lngate(float* __restrict__ merged,
              const float* __restrict__ z1, const float* __restrict__ z2,
              const float* __restrict__ n1w, const float* __restrict__ n1b,
              const float* __restrict__ n2w, const float* __restrict__ n2b) {
  int w = threadIdx.x >> 6, lane = threadIdx.x & 63;
  int rowbase = (blockIdx.x * 4 + w) * 8;     // grid 1024 x 4 waves x 8 rows = 32768 rows
#pragma unroll 1
  for (int rr = 0; rr < 8; rr++) {
    int row = rowbase + rr;
    int m = row & 1, blpos = row >> 1;
    const float* gr = merged + (size_t)row * CI;
    float v0 = gr[lane], v1 = gr[lane + 64], v2 = gr[lane + 128];
    float s1 = v0 + v1 + v2;
    float s2 = v0 * v0 + v1 * v1 + v2 * v2;
#pragma unroll
    for (int o = 32; o > 0; o >>= 1) {
      s1 += __shfl_xor(s1, o);
      s2 += __shfl_xor(s2, o);
    }
    float mean = s1 * (1.f / CI);
    float var = s2 * (1.f / CI) - mean * mean;
    float rstd = rsqrtf(var + 1e-5f);
    const float* nw = m ? n2w : n1w;
    const float* nb = m ? n2b : n1b;
    const float* zr = (m ? z2 : z1) + (size_t)blpos * CI;
    float* go = merged + (size_t)row * CI;
#pragma unroll
    for (int e = 0; e < 3; e++) {
      int cc = lane + e * 64;
      float v = e == 0 ? v0 : (e == 1 ? v1 : v2);
      float vn = (v - mean) * rstd * nw[cc] + nb[cc];
      float z = zr[cc];
      go[cc] = vn * (z / (1.f + __expf(-z)));
    }
  }
}

// ---------------- out_proj: LDS-tiled GEMM. M=16384, N=96, K=192 (2 chunks) ----------------
__global__ __launch_bounds__(256)
void k_outproj(const float* __restrict__ g,
               const float* __restrict__ w1, const float* __restrict__ w2,
               float* __restrict__ out) {
  int mb = blockIdx.x;
  int m  = blockIdx.y;
  const float* w = m ? w2 : w1;
  __shared__ float As[64][100];
  __shared__ float Ws[96][98];
  int t = threadIdx.x;
  int tc = t & 15, tr = t >> 4;
  float acc[4][6] = {};
  for (int kc = 0; kc < 2; kc++) {
    if (kc) __syncthreads();
    for (int i = t; i < 1536; i += 256) {
      int r = i / 24, kk = (i % 24) * 4;
      *(float4*)&As[r][kk] =
          *(const float4*)&g[((size_t)(mb * 64 + r) * 2 + m) * CI + kc * 96 + kk];
    }
    for (int i = t; i < 4608; i += 256) {
      int r = i / 48, kk = (i % 48) * 2;
      *(float2*)&Ws[r][kk] = *(const float2*)&w[(size_t)r * CI + kc * 96 + kk];
    }
    __syncthreads();
    for (int k = 0; k < 96; k += 2) {
      float2 a[4], b[6];
#pragma unroll
      for (int i = 0; i < 4; i++) a[i] = *(const float2*)&As[tr * 4 + i][k];
#pragma unroll
      for (int j = 0; j < 6; j++) b[j] = *(const float2*)&Ws[tc * 6 + j][k];
#pragma unroll
      for (int i = 0; i < 4; i++)
#pragma unroll
        for (int j = 0; j < 6; j++) {
          acc[i][j] = fmaf(a[i].x, b[j].x, acc[i][j]);
          acc[i][j] = fmaf(a[i].y, b[j].y, acc[i][j]);
        }
    }
  }
  float* outp = out + (size_t)m * (BB * LL * DM);
#pragma unroll
  for (int i = 0; i < 4; i++) {
    size_t bl = (size_t)mb * 64 + tr * 4 + i;
#pragma unroll
    for (int j = 0; j < 6; j++)
      outp[bl * DM + tc * 6 + j] = acc[i][j];
  }
}

extern "C" void kernel_launch(void* const* d_in, const int* in_sizes, int n_in,
                              void* d_out, int out_size, void* d_ws, size_t ws_size,
                              hipStream_t stream) {
  const float* rgb = (const float*)d_in[0];
  const float* tin = (const float*)d_in[1];
  const float* ip1 = (const float*)d_in[2];
  const float* ip2 = (const float*)d_in[3];
  const float* c1w = (const float*)d_in[4];
  const float* c1b = (const float*)d_in[5];
  const float* c2w = (const float*)d_in[6];
  const float* c2b = (const float*)d_in[7];
  const float* wx  = (const float*)d_in[8];
  const float* dtw = (const float*)d_in[9];
  const float* dtb = (const float*)d_in[10];
  const float* alg = (const float*)d_in[11];
  const float* Dsp = (const float*)d_in[12];
  const float* n1w = (const float*)d_in[13];
  const float* n1b = (const float*)d_in[14];
  const float* n2w = (const float*)d_in[15];
  const float* n2b = (const float*)d_in[16];
  const float* op1 = (const float*)d_in[17];
  const float* op2 = (const float*)d_in[18];

  float* ws = (float*)d_ws;
  float* xp1 = ws + OFF_XPRE1;
  float* xp2 = ws + OFF_XPRE2;
  float* z1  = ws + OFF_Z1;
  float* z2  = ws + OFF_Z2;
  float* x1c = ws + OFF_X1C;
  float* x2c = ws + OFF_X2C;
  float* dbl = ws + OFF_DBL;
  float* mg  = ws + OFF_MERG;
  float* dsm = ws + OFF_DSUM;
  // hend lives in the mg region (pass1 -> prop only; memset erases it afterwards).
  // hin spans xp1+xp2 (dead after k_conv): SS*BKT*CI*NN = 6291456 floats, exact fit.
  float* he  = ws + OFF_MERG;
  float* hi  = ws + OFF_XPRE1;
  float* out = (float*)d_out;

  k_inproj<<<dim3(256, 4, 2), 256, 0, stream>>>(rgb, tin, ip1, ip2, xp1, xp2, z1, z2);
  k_conv<<<dim3(12288, 2), 256, 0, stream>>>(xp1, xp2, c1w, c1b, c2w, c2b, x1c, x2c);
  k_dbl<<<dim3(128, 8), 256, 0, stream>>>(x1c, x2c, wx, dbl);
  k_scan<1><<<SS * BKT, 192, 0, stream>>>(x1c, x2c, dbl, dtw, dtb, alg, Dsp, he, dsm, hi, mg);
  k_prop<<<192, 256, 0, stream>>>(he, dsm, alg, hi);
  // zero the merge accumulator only now (hend is dead after k_prop)
  hipMemsetAsync(mg, 0, (size_t)6291456 * sizeof(float), stream);
  k_scan<2><<<SS * BKT, 192, 0, stream>>>(x1c, x2c, dbl, dtw, dtb, alg, Dsp, he, dsm, hi, mg);
  k_lngate<<<1024, 256, 0, stream>>>(mg, z1, z2, n1w, n1b, n2w, n2b);
  k_outproj<<<dim3(256, 2), 256, 0, stream>>>(mg, op1, op2, out);
}

// Round 15
// 418.871 us; speedup vs baseline: 1.0640x; 1.0640x over previous
//
#include <hip/hip_runtime.h>
#include <math.h>

// Problem constants
#define BB   4
#define LL   4096          // H*W
#define L2T  8192          // 2*L (modality-interleaved sequence)
#define DM   96            // D_MODEL
#define CI   192           // D_INNER
#define KD   4             // K directions
#define NN   16            // D_STATE
#define RR   6             // DT_RANK
#define BKT  16            // B*K
#define SS   128           // scan segments
#define TT   64            // steps per segment = L2T/SS
#define DBLS 40            // padded row stride for x_dbl (38 -> 40 for float4)
#define CHS  16            // steps per LDS-staged chunk
#define NCH  (TT / CHS)    // 4 chunks per segment

// Workspace layout (float offsets) — identical to R9/R11/R13 (proven passing incl. post-timing)
#define OFF_XPRE1 0
#define OFF_XPRE2 3145728
#define OFF_Z1    6291456
#define OFF_Z2    9437184
#define OFF_X1C   12582912
#define OFF_X2C   15728640
#define OFF_DBL   18874368   // BKT*L2T*40 = 5242880
#define OFF_MERG  24117248   // B*L*2*CI = 6291456 == SS*BKT*CI*NN (hend fits exactly)
#define OFF_DSUM  30408704   // SS*BKT*CI = 393216

// ---------------- in_proj: LDS-tiled GEMM. M=16384, N=384 (4 tiles of 96), K=96 ----------------
__global__ __launch_bounds__(256)
void k_inproj(const float* __restrict__ rgb, const float* __restrict__ tin,
              const float* __restrict__ w1, const float* __restrict__ w2,
              float* __restrict__ xp1, float* __restrict__ xp2,
              float* __restrict__ zz1, float* __restrict__ zz2) {
  int mb = blockIdx.x;     // row tile
  int nb = blockIdx.y;     // col tile (0..3)
  int m  = blockIdx.z;     // modality
  const float* in = m ? tin : rgb;
  const float* w  = (m ? w2 : w1) + nb * 96 * DM;
  __shared__ float As[64][100];
  __shared__ float Ws[96][98];
  int t = threadIdx.x;
  const float4* asrc = (const float4*)(in + (size_t)mb * 64 * DM);
  for (int i = t; i < 1536; i += 256) {
    int r = i / 24, kk = (i % 24) * 4;
    *(float4*)&As[r][kk] = asrc[i];
  }
  const float2* wsrc = (const float2*)w;
  for (int i = t; i < 4608; i += 256) {
    int r = i / 48, kk = (i % 48) * 2;
    *(float2*)&Ws[r][kk] = wsrc[i];
  }
  __syncthreads();
  int tc = t & 15, tr = t >> 4;
  float acc[4][6] = {};
  for (int k = 0; k < 96; k += 2) {
    float2 a[4], b[6];
#pragma unroll
    for (int i = 0; i < 4; i++) a[i] = *(const float2*)&As[tr * 4 + i][k];
#pragma unroll
    for (int j = 0; j < 6; j++) b[j] = *(const float2*)&Ws[tc * 6 + j][k];
#pragma unroll
    for (int i = 0; i < 4; i++)
#pragma unroll
      for (int j = 0; j < 6; j++) {
        acc[i][j] = fmaf(a[i].x, b[j].x, acc[i][j]);
        acc[i][j] = fmaf(a[i].y, b[j].y, acc[i][j]);
      }
  }
  float* dst = (nb < 2) ? (m ? xp2 : xp1) : (m ? zz2 : zz1);
  int colbase = (nb & 1) * 96 + tc * 6;
#pragma unroll
  for (int i = 0; i < 4; i++) {
    size_t bl = (size_t)mb * 64 + tr * 4 + i;
#pragma unroll
    for (int j = 0; j < 6; j++)
      dst[bl * CI + colbase + j] = acc[i][j];
  }
}

// ---------------- depthwise 3x3 conv (SAME, zero pad) + bias + SiLU ----------------
__global__ __launch_bounds__(256)
void k_conv(const float* __restrict__ xp1, const float* __restrict__ xp2,
            const float* __restrict__ c1w, const float* __restrict__ c1b,
            const float* __restrict__ c2w, const float* __restrict__ c2b,
            float* __restrict__ o1, float* __restrict__ o2) {
  int m = blockIdx.y;
  const float* in = m ? xp2 : xp1;
  const float* cw = m ? c2w : c1w;
  const float* cb = m ? c2b : c1b;
  float* out = m ? o2 : o1;
  int idx = blockIdx.x * 256 + threadIdx.x;
  int c = idx % CI;
  int bl = idx / CI;
  int b = bl / LL, l = bl % LL;
  int hh = l >> 6, ww = l & 63;
  float a = cb[c];
#pragma unroll
  for (int di = 0; di < 3; di++) {
    int h2 = hh + di - 1;
    if ((unsigned)h2 >= 64u) continue;
#pragma unroll
    for (int dj = 0; dj < 3; dj++) {
      int w2 = ww + dj - 1;
      if ((unsigned)w2 >= 64u) continue;
      a = fmaf(in[(b * LL + h2 * 64 + w2) * CI + c], cw[c * 9 + di * 3 + dj], a);
    }
  }
  out[idx] = a / (1.f + __expf(-a));
}

// ---------------- x_dbl projection as tiled GEMM per (b,k) ----------------
__global__ __launch_bounds__(256)
void k_dbl(const float* __restrict__ x1c, const float* __restrict__ x2c,
           const float* __restrict__ wx, float* __restrict__ dbl) {
  int pt = blockIdx.x;
  int bk = blockIdx.y;
  int b = bk >> 2, k = bk & 3;
  __shared__ float As[64][100];
  __shared__ float Ws[40][100];
  int t = threadIdx.x;
  int tc = t & 7, tr = t >> 3;
  float acc[2][5] = {};
  for (int kc = 0; kc < 2; kc++) {
    if (kc) __syncthreads();
    for (int i = t; i < 1536; i += 256) {
      int r = i / 24, kk = (i % 24) * 4;
      int l2 = pt * 64 + r;
      int mm = l2 & 1, l = l2 >> 1;
      int lt = (k >= 2) ? (LL - 1 - l) : l;
      int sp = (k & 1) ? (((lt & 63) << 6) | (lt >> 6)) : lt;
      const float* src = (mm ? x2c : x1c) + ((size_t)(b * LL + sp)) * CI + kc * 96;
      *(float4*)&As[r][kk] = *(const float4*)(src + kk);
    }
    for (int i = t; i < 960; i += 256) {
      int r = i / 24, kk = (i % 24) * 4;
      float4 v;
      if (r < 38) v = *(const float4*)&wx[(size_t)(k * 38 + r) * CI + kc * 96 + kk];
      else        v = float4{0.f, 0.f, 0.f, 0.f};
      *(float4*)&Ws[r][kk] = v;
    }
    __syncthreads();
    for (int kk2 = 0; kk2 < 96; kk2 += 2) {
      float2 a[2], bv[5];
#pragma unroll
      for (int i = 0; i < 2; i++) a[i] = *(const float2*)&As[tr * 2 + i][kk2];
#pragma unroll
      for (int j = 0; j < 5; j++) bv[j] = *(const float2*)&Ws[tc * 5 + j][kk2];
#pragma unroll
      for (int i = 0; i < 2; i++)
#pragma unroll
        for (int j = 0; j < 5; j++) {
          acc[i][j] = fmaf(a[i].x, bv[j].x, acc[i][j]);
          acc[i][j] = fmaf(a[i].y, bv[j].y, acc[i][j]);
        }
    }
  }
#pragma unroll
  for (int i = 0; i < 2; i++) {
    size_t row = (size_t)bk * L2T + pt * 64 + tr * 2 + i;
#pragma unroll
    for (int j = 0; j < 5; j++) {
      int cc = tc * 5 + j;
      if (cc < 38) dbl[row * DBLS + cc] = acc[i][j];
    }
  }
}

// ---------------- segmented selective scan: 192-thread blocks, LDS-staged rows ----------------
// R11/R13 geometry (block = 3 c-group waves of one (bk,s), 2048 blocks = 8/CU). Row data now
// staged into LDS double-buffered chunks (16 steps = 2560B) via register-staged vector loads
// issued a full chunk (~6400cy) ahead, consumed with ds_read_b128 broadcast (same-address =
// conflict-free) under compiler-counted lgkmcnt — removing the per-pair s_load lgkmcnt(0) drain.
template<int PASS>
__global__ __launch_bounds__(192)
void k_scan(const float* __restrict__ x1c, const float* __restrict__ x2c,
            const float* __restrict__ dbl,
            const float* __restrict__ dtw, const float* __restrict__ dtb,
            const float* __restrict__ alogs, const float* __restrict__ dsv,
            float* __restrict__ hend, float* __restrict__ dsum,
            const float* __restrict__ hin, float* __restrict__ merged) {
  __shared__ float sd[2][CHS * DBLS];   // 2 x 640 floats = 5120 B
  int bid = blockIdx.x;          // SS*BKT
  int s  = bid & (SS - 1);
  int bk = bid >> 7;             // 0..15
  int b = bk >> 2, kdir = bk & 3;
  int c = threadIdx.x;           // 0..191 (wave w covers c in [w*64, w*64+64))
  int kc = kdir * CI + c;

  float w2r0 = dtw[kc * RR + 0], w2r1 = dtw[kc * RR + 1], w2r2 = dtw[kc * RR + 2];
  float w2r3 = dtw[kc * RR + 3], w2r4 = dtw[kc * RR + 4], w2r5 = dtw[kc * RR + 5];
  float bias = dtb[kc];
  float Dv   = (PASS == 2) ? dsv[kc] : 0.f;
  float Areg[NN];
#pragma unroll
  for (int n = 0; n < NN; n++) Areg[n] = -__expf(alogs[kc * NN + n]);
  float A1 = Areg[0];
  int ok = 1;
#pragma unroll
  for (int n = 1; n < NN; n++) {
    float want = A1 * (float)(n + 1);
    if (!(fabsf(Areg[n] - want) <= fabsf(want) * 1e-3f + 1e-6f)) ok = 0;
  }
  const bool structured = (__all(ok) != 0);   // A[n] = (n+1)*A1 -> dA[n] = r^(n+1)

  float h[NN];
  if (PASS == 2) {
    int base = ((s * BKT + bk) * CI + c) * NN;
#pragma unroll
    for (int n = 0; n < NN; n++) h[n] = hin[base + n];
  } else {
#pragma unroll
    for (int n = 0; n < NN; n++) h[n] = 0.f;
  }
  float dacc = 0.f;

  const float* dpf = dbl + (size_t)(bk * L2T + s * TT) * DBLS;   // block-uniform segment base
  const float* u1b = x1c + (size_t)b * LL * CI + c;
  const float* u2b = x2c + (size_t)b * LL * CI + c;

  auto spmap = [&](int l) -> int {
    int lt = (kdir >= 2) ? (LL - 1 - l) : l;
    return (kdir & 1) ? (((lt & 63) << 6) | (lt >> 6)) : lt;
  };

  // register-staged chunk load / LDS write (160 of 192 threads carry 16B each = 2560B)
  auto ldchunk = [&](int ch) -> float4 {
    if (threadIdx.x < 160)
      return *(const float4*)(dpf + ch * (CHS * DBLS) + threadIdx.x * 4);
    return float4{0.f, 0.f, 0.f, 0.f};
  };
  auto wrchunk = [&](int bufi, float4 v) {
    if (threadIdx.x < 160)
      *(float4*)&sd[bufi][threadIdx.x * 4] = v;
  };

#define DG(Q, i) ((i & 3) == 0 ? Q[(i) >> 2].x : (i & 3) == 1 ? Q[(i) >> 2].y : (i & 3) == 2 ? Q[(i) >> 2].z : Q[(i) >> 2].w)

  // one scan step; Q points at the step's 40-float row in LDS (quads ds_read + broadcast)
  auto step = [&](const float4* Q, float u, float& y) {
    float x = bias;
    x = fmaf(DG(Q, 0), w2r0, x); x = fmaf(DG(Q, 1), w2r1, x); x = fmaf(DG(Q, 2), w2r2, x);
    x = fmaf(DG(Q, 3), w2r3, x); x = fmaf(DG(Q, 4), w2r4, x); x = fmaf(DG(Q, 5), w2r5, x);
    float delta = (x > 15.f) ? x : __logf(1.f + __expf(x));
    float du = delta * u;
    float y0 = 0.f, y1 = 0.f, y2 = 0.f, y3 = 0.f;
    if (structured) {
      float r  = __expf(delta * A1);
      float r2 = r * r, r3 = r2 * r, r4 = r2 * r2;
      float r6 = r4 * r2, r8 = r4 * r4;
      float pw[NN];
      pw[0] = r;       pw[1] = r2;      pw[2] = r3;      pw[3] = r4;
      pw[4] = r4 * r;  pw[5] = r6;      pw[6] = r4 * r3; pw[7] = r8;
      pw[8] = r8 * r;  pw[9] = r8 * r2; pw[10] = r8 * r3; pw[11] = r8 * r4;
      pw[12] = r8 * pw[4]; pw[13] = r8 * r6; pw[14] = r8 * pw[6]; pw[15] = r8 * r8;
#pragma unroll
      for (int n = 0; n < NN; n++) {
        h[n] = fmaf(h[n], pw[n], du * DG(Q, 6 + n));
        if (PASS == 2) {
          float* yp = (n & 2) ? ((n & 1) ? &y3 : &y2) : ((n & 1) ? &y1 : &y0);
          *yp = fmaf(h[n], DG(Q, 22 + n), *yp);
        }
      }
    } else {
#pragma unroll
      for (int n = 0; n < NN; n++) {
        float dA = __expf(delta * Areg[n]);
        h[n] = fmaf(h[n], dA, du * DG(Q, 6 + n));
        if (PASS == 2) {
          float* yp = (n & 2) ? ((n & 1) ? &y3 : &y2) : ((n & 1) ? &y1 : &y0);
          *yp = fmaf(h[n], DG(Q, 22 + n), *yp);
        }
      }
    }
    if (PASS == 1) dacc += delta;
    else y = fmaf(u, Dv, (y0 + y1) + (y2 + y3));
  };

  const int NP = TT / 2;         // pairs
  int l0 = (s * TT) >> 1;
  // u pipeline prologue (3 deep, as R13)
  int spC = spmap(l0);
  float u1C = u1b[(size_t)spC * CI];
  float u2C = u2b[(size_t)spC * CI];
  int spN = spmap(l0 + 1);
  float u1N = u1b[(size_t)spN * CI];
  float u2N = u2b[(size_t)spN * CI];
  int spN2 = spmap(l0 + 2);
  float u1N2 = u1b[(size_t)spN2 * CI];
  float u2N2 = u2b[(size_t)spN2 * CI];
  // LDS staging prologue: chunk0 written, chunk1 in flight
  float4 stg = ldchunk(0);
  wrchunk(0, stg);
  stg = ldchunk(1);
  __syncthreads();

#pragma unroll 1
  for (int ch = 0; ch < NCH; ch++) {
    const float* cb = sd[ch & 1];
#pragma unroll 1
    for (int pp = 0; pp < CHS / 2; pp++) {
      int p = (ch * CHS) / 2 + pp;
      const float4* qA = (const float4*)&cb[(pp * 2) * DBLS];
      const float4* qB = (const float4*)&cb[(pp * 2 + 1) * DBLS];
      // issue pair p+3's u loads (2 pairs of slack beyond the one shifted in)
      int spN3 = 0; float u1N3 = 0.f, u2N3 = 0.f;
      if (p + 3 < NP) {
        spN3 = spmap(l0 + p + 3);
        u1N3 = u1b[(size_t)spN3 * CI];
        u2N3 = u2b[(size_t)spN3 * CI];
      }
      float ya, yb;
      step(qA, u1C, ya);                      // even step: modality rgb (m=0)
      step(qB, u2C, yb);                      // odd step: modality t (m=1)
      if (PASS == 2) {
        float* mrow = merged + (size_t)(b * LL + spC) * (2 * CI) + c;
        atomicAdd(mrow, ya);
        atomicAdd(mrow + CI, yb);
      }
      spC = spN;  u1C = u1N;  u2C = u2N;
      spN = spN2; u1N = u1N2; u2N = u2N2;
      spN2 = spN3; u1N2 = u1N3; u2N2 = u2N3;
    }
    if (ch + 1 < NCH) {
      wrchunk((ch + 1) & 1, stg);             // overwrites chunk ch-1's buffer (barrier-protected)
      if (ch + 2 < NCH) stg = ldchunk(ch + 2);
      __syncthreads();
    }
  }
#undef DG

  if (PASS == 1) {
    int base = ((s * BKT + bk) * CI + c) * NN;
#pragma unroll
    for (int n = 0; n < NN; n++) hend[base + n] = h[n];
    dsum[(s * BKT + bk) * CI + c] = dacc;
  }
}

// ---------------- propagate segment initial states (two-buffer) ----------------
__global__ __launch_bounds__(256)
void k_prop(const float* __restrict__ hend, const float* __restrict__ dsum,
            const float* __restrict__ alogs, float* __restrict__ hin) {
  int idx = blockIdx.x * 256 + threadIdx.x;   // BKT*CI*NN = 49152
  int n = idx & 15;
  int rest = idx >> 4;
  int c = rest % CI;
  int bk = rest / CI;
  int k = bk & 3;
  float A = -__expf(alogs[(k * CI + c) * NN + n]);
  float h = 0.f;
  for (int s = 0; s < SS; s++) {
    int cell = (s * BKT + bk) * CI + c;
    hin[cell * NN + n] = h;
    float ap = __expf(A * dsum[cell]);
    h = h * ap + hend[cell * NN + n];
  }
}

// ---------------- LayerNorm over CI + SiLU(z) gate (in-place on merged) ----------------
__global__ __launch_bounds__(192)
void k_lngate(float* __restrict__ merged,
              const float* __restrict__ z1, const float* __restrict__ z2,
              const float* __restrict__ n1w, const float* __restrict__ n1b,
              const float* __restrict__ n2w, const float* __restrict__ n2b) {
  int bid = blockIdx.x;
  int m = bid & 1;
  int bl = bid >> 1;
  int c = threadIdx.x;
  float v = merged[(size_t)bid * CI + c];
  float s1 = v, s2 = v * v;
  for (int o = 32; o > 0; o >>= 1) {
    s1 += __shfl_xor(s1, o);
    s2 += __shfl_xor(s2, o);
  }
  __shared__ float red[2][3];
  int wv = threadIdx.x >> 6, ln = threadIdx.x & 63;
  if (ln == 0) { red[0][wv] = s1; red[1][wv] = s2; }
  __syncthreads();
  float S1 = red[0][0] + red[0][1] + red[0][2];
  float S2 = red[1][0] + red[1][1] + red[1][2];
  float mean = S1 * (1.f / CI);
  float var = S2 * (1.f / CI) - mean * mean;
  float rstd = rsqrtf(var + 1e-5f);
  const float* nw = m ? n2w : n1w;
  const float* nb = m ? n2b : n1b;
  float vn = (v - mean) * rstd * nw[c] + nb[c];
  float z = (m ? z2 : z1)[(size_t)bl * CI + c];
  float g = vn * (z / (1.f + __expf(-z)));
  merged[(size_t)bid * CI + c] = g;
}

// ---------------- out_proj: LDS-tiled GEMM. M=16384, N=96, K=192 (2 chunks) ----------------
__global__ __launch_bounds__(256)
void k_outproj(const float* __restrict__ g,
               const float* __restrict__ w1, const float* __restrict__ w2,
               float* __restrict__ out) {
  int mb = blockIdx.x;
  int m  = blockIdx.y;
  const float* w = m ? w2 : w1;
  __shared__ float As[64][100];
  __shared__ float Ws[96][98];
  int t = threadIdx.x;
  int tc = t & 15, tr = t >> 4;
  float acc[4][6] = {};
  for (int kc = 0; kc < 2; kc++) {
    if (kc) __syncthreads();
    for (int i = t; i < 1536; i += 256) {
      int r = i / 24, kk = (i % 24) * 4;
      *(float4*)&As[r][kk] =
          *(const float4*)&g[((size_t)(mb * 64 + r) * 2 + m) * CI + kc * 96 + kk];
    }
    for (int i = t; i < 4608; i += 256) {
      int r = i / 48, kk = (i % 48) * 2;
      *(float2*)&Ws[r][kk] = *(const float2*)&w[(size_t)r * CI + kc * 96 + kk];
    }
    __syncthreads();
    for (int k = 0; k < 96; k += 2) {
      float2 a[4], b[6];
#pragma unroll
      for (int i = 0; i < 4; i++) a[i] = *(const float2*)&As[tr * 4 + i][k];
#pragma unroll
      for (int j = 0; j < 6; j++) b[j] = *(const float2*)&Ws[tc * 6 + j][k];
#pragma unroll
      for (int i = 0; i < 4; i++)
#pragma unroll
        for (int j = 0; j < 6; j++) {
          acc[i][j] = fmaf(a[i].x, b[j].x, acc[i][j]);
          acc[i][j] = fmaf(a[i].y, b[j].y, acc[i][j]);
        }
    }
  }
  float* outp = out + (size_t)m * (BB * LL * DM);
#pragma unroll
  for (int i = 0; i < 4; i++) {
    size_t bl = (size_t)mb * 64 + tr * 4 + i;
#pragma unroll
    for (int j = 0; j < 6; j++)
      outp[bl * DM + tc * 6 + j] = acc[i][j];
  }
}

extern "C" void kernel_launch(void* const* d_in, const int* in_sizes, int n_in,
                              void* d_out, int out_size, void* d_ws, size_t ws_size,
                              hipStream_t stream) {
  const float* rgb = (const float*)d_in[0];
  const float* tin = (const float*)d_in[1];
  const float* ip1 = (const float*)d_in[2];
  const float* ip2 = (const float*)d_in[3];
  const float* c1w = (const float*)d_in[4];
  const float* c1b = (const float*)d_in[5];
  const float* c2w = (const float*)d_in[6];
  const float* c2b = (const float*)d_in[7];
  const float* wx  = (const float*)d_in[8];
  const float* dtw = (const float*)d_in[9];
  const float* dtb = (const float*)d_in[10];
  const float* alg = (const float*)d_in[11];
  const float* Dsp = (const float*)d_in[12];
  const float* n1w = (const float*)d_in[13];
  const float* n1b = (const float*)d_in[14];
  const float* n2w = (const float*)d_in[15];
  const float* n2b = (const float*)d_in[16];
  const float* op1 = (const float*)d_in[17];
  const float* op2 = (const float*)d_in[18];

  float* ws = (float*)d_ws;
  float* xp1 = ws + OFF_XPRE1;
  float* xp2 = ws + OFF_XPRE2;
  float* z1  = ws + OFF_Z1;
  float* z2  = ws + OFF_Z2;
  float* x1c = ws + OFF_X1C;
  float* x2c = ws + OFF_X2C;
  float* dbl = ws + OFF_DBL;
  float* mg  = ws + OFF_MERG;
  float* dsm = ws + OFF_DSUM;
  // hend lives in the mg region (pass1 -> prop only; memset erases it afterwards).
  // hin spans xp1+xp2 (dead after k_conv): SS*BKT*CI*NN = 6291456 floats, exact fit.
  float* he  = ws + OFF_MERG;
  float* hi  = ws + OFF_XPRE1;
  float* out = (float*)d_out;

  k_inproj<<<dim3(256, 4, 2), 256, 0, stream>>>(rgb, tin, ip1, ip2, xp1, xp2, z1, z2);
  k_conv<<<dim3(12288, 2), 256, 0, stream>>>(xp1, xp2, c1w, c1b, c2w, c2b, x1c, x2c);
  k_dbl<<<dim3(128, 16), 256, 0, stream>>>(x1c, x2c, wx, dbl);
  k_scan<1><<<SS * BKT, 192, 0, stream>>>(x1c, x2c, dbl, dtw, dtb, alg, Dsp, he, dsm, hi, mg);
  k_prop<<<192, 256, 0, stream>>>(he, dsm, alg, hi);
  // zero the merge accumulator only now (hend is dead after k_prop)
  hipMemsetAsync(mg, 0, (size_t)6291456 * sizeof(float), stream);
  k_scan<2><<<SS * BKT, 192, 0, stream>>>(x1c, x2c, dbl, dtw, dtb, alg, Dsp, he, dsm, hi, mg);
  k_lngate<<<BB * LL * 2, 192, 0, stream>>>(mg, z1, z2, n1w, n1b, n2w, n2b);
  k_outproj<<<dim3(256, 2), 256, 0, stream>>>(mg, op1, op2, out);
}

// Round 16
// 417.916 us; speedup vs baseline: 1.0665x; 1.0023x over previous
//
#include <hip/hip_runtime.h>
#include <math.h>

// Problem constants
#define BB   4
#define LL   4096          // H*W
#define L2T  8192          // 2*L (modality-interleaved sequence)
#define DM   96            // D_MODEL
#define CI   192           // D_INNER
#define KD   4             // K directions
#define NN   16            // D_STATE
#define RR   6             // DT_RANK
#define BKT  16            // B*K
#define SS   128           // scan segments
#define TT   64            // steps per segment = L2T/SS
#define DBLS 40            // padded row stride for x_dbl (38 -> 40 for float4)
#define CHS  16            // steps per LDS-staged chunk
#define NCH  (TT / CHS)    // 4 chunks per segment

// Workspace layout (float offsets) — identical to R9/R11/R13/R15 (proven)
#define OFF_XPRE1 0
#define OFF_XPRE2 3145728
#define OFF_Z1    6291456
#define OFF_Z2    9437184
#define OFF_X1C   12582912
#define OFF_X2C   15728640
#define OFF_DBL   18874368   // BKT*L2T*40 = 5242880
#define OFF_MERG  24117248   // B*L*2*CI = 6291456 == SS*BKT*CI*NN (hend fits exactly)
#define OFF_DSUM  30408704   // SS*BKT*CI = 393216

typedef float f2 __attribute__((ext_vector_type(2)));
static __device__ __forceinline__ f2 fma2(f2 a, f2 b, f2 c) {
  return __builtin_elementwise_fma(a, b, c);
}

// ---------------- in_proj: LDS-tiled GEMM. M=16384, N=384 (4 tiles of 96), K=96 ----------------
__global__ __launch_bounds__(256)
void k_inproj(const float* __restrict__ rgb, const float* __restrict__ tin,
              const float* __restrict__ w1, const float* __restrict__ w2,
              float* __restrict__ xp1, float* __restrict__ xp2,
              float* __restrict__ zz1, float* __restrict__ zz2) {
  int mb = blockIdx.x;     // row tile
  int nb = blockIdx.y;     // col tile (0..3)
  int m  = blockIdx.z;     // modality
  const float* in = m ? tin : rgb;
  const float* w  = (m ? w2 : w1) + nb * 96 * DM;
  __shared__ float As[64][100];
  __shared__ float Ws[96][98];
  int t = threadIdx.x;
  const float4* asrc = (const float4*)(in + (size_t)mb * 64 * DM);
  for (int i = t; i < 1536; i += 256) {
    int r = i / 24, kk = (i % 24) * 4;
    *(float4*)&As[r][kk] = asrc[i];
  }
  const float2* wsrc = (const float2*)w;
  for (int i = t; i < 4608; i += 256) {
    int r = i / 48, kk = (i % 48) * 2;
    *(float2*)&Ws[r][kk] = wsrc[i];
  }
  __syncthreads();
  int tc = t & 15, tr = t >> 4;
  float acc[4][6] = {};
  for (int k = 0; k < 96; k += 2) {
    float2 a[4], b[6];
#pragma unroll
    for (int i = 0; i < 4; i++) a[i] = *(const float2*)&As[tr * 4 + i][k];
#pragma unroll
    for (int j = 0; j < 6; j++) b[j] = *(const float2*)&Ws[tc * 6 + j][k];
#pragma unroll
    for (int i = 0; i < 4; i++)
#pragma unroll
      for (int j = 0; j < 6; j++) {
        acc[i][j] = fmaf(a[i].x, b[j].x, acc[i][j]);
        acc[i][j] = fmaf(a[i].y, b[j].y, acc[i][j]);
      }
  }
  float* dst = (nb < 2) ? (m ? xp2 : xp1) : (m ? zz2 : zz1);
  int colbase = (nb & 1) * 96 + tc * 6;
#pragma unroll
  for (int i = 0; i < 4; i++) {
    size_t bl = (size_t)mb * 64 + tr * 4 + i;
#pragma unroll
    for (int j = 0; j < 6; j++)
      dst[bl * CI + colbase + j] = acc[i][j];
  }
}

// ---------------- depthwise 3x3 conv (SAME, zero pad) + bias + SiLU ----------------
__global__ __launch_bounds__(256)
void k_conv(const float* __restrict__ xp1, const float* __restrict__ xp2,
            const float* __restrict__ c1w, const float* __restrict__ c1b,
            const float* __restrict__ c2w, const float* __restrict__ c2b,
            float* __restrict__ o1, float* __restrict__ o2) {
  int m = blockIdx.y;
  const float* in = m ? xp2 : xp1;
  const float* cw = m ? c2w : c1w;
  const float* cb = m ? c2b : c1b;
  float* out = m ? o2 : o1;
  int idx = blockIdx.x * 256 + threadIdx.x;
  int c = idx % CI;
  int bl = idx / CI;
  int b = bl / LL, l = bl % LL;
  int hh = l >> 6, ww = l & 63;
  float a = cb[c];
#pragma unroll
  for (int di = 0; di < 3; di++) {
    int h2 = hh + di - 1;
    if ((unsigned)h2 >= 64u) continue;
#pragma unroll
    for (int dj = 0; dj < 3; dj++) {
      int w2 = ww + dj - 1;
      if ((unsigned)w2 >= 64u) continue;
      a = fmaf(in[(b * LL + h2 * 64 + w2) * CI + c], cw[c * 9 + di * 3 + dj], a);
    }
  }
  out[idx] = a / (1.f + __expf(-a));
}

// ---------------- x_dbl projection as tiled GEMM per (b,k) ----------------
__global__ __launch_bounds__(256)
void k_dbl(const float* __restrict__ x1c, const float* __restrict__ x2c,
           const float* __restrict__ wx, float* __restrict__ dbl) {
  int pt = blockIdx.x;
  int bk = blockIdx.y;
  int b = bk >> 2, k = bk & 3;
  __shared__ float As[64][100];
  __shared__ float Ws[40][100];
  int t = threadIdx.x;
  int tc = t & 7, tr = t >> 3;
  float acc[2][5] = {};
  for (int kc = 0; kc < 2; kc++) {
    if (kc) __syncthreads();
    for (int i = t; i < 1536; i += 256) {
      int r = i / 24, kk = (i % 24) * 4;
      int l2 = pt * 64 + r;
      int mm = l2 & 1, l = l2 >> 1;
      int lt = (k >= 2) ? (LL - 1 - l) : l;
      int sp = (k & 1) ? (((lt & 63) << 6) | (lt >> 6)) : lt;
      const float* src = (mm ? x2c : x1c) + ((size_t)(b * LL + sp)) * CI + kc * 96;
      *(float4*)&As[r][kk] = *(const float4*)(src + kk);
    }
    for (int i = t; i < 960; i += 256) {
      int r = i / 24, kk = (i % 24) * 4;
      float4 v;
      if (r < 38) v = *(const float4*)&wx[(size_t)(k * 38 + r) * CI + kc * 96 + kk];
      else        v = float4{0.f, 0.f, 0.f, 0.f};
      *(float4*)&Ws[r][kk] = v;
    }
    __syncthreads();
    for (int kk2 = 0; kk2 < 96; kk2 += 2) {
      float2 a[2], bv[5];
#pragma unroll
      for (int i = 0; i < 2; i++) a[i] = *(const float2*)&As[tr * 2 + i][kk2];
#pragma unroll
      for (int j = 0; j < 5; j++) bv[j] = *(const float2*)&Ws[tc * 5 + j][kk2];
#pragma unroll
      for (int i = 0; i < 2; i++)
#pragma unroll
        for (int j = 0; j < 5; j++) {
          acc[i][j] = fmaf(a[i].x, bv[j].x, acc[i][j]);
          acc[i][j] = fmaf(a[i].y, bv[j].y, acc[i][j]);
        }
    }
  }
#pragma unroll
  for (int i = 0; i < 2; i++) {
    size_t row = (size_t)bk * L2T + pt * 64 + tr * 2 + i;
#pragma unroll
    for (int j = 0; j < 5; j++) {
      int cc = tc * 5 + j;
      if (cc < 38) dbl[row * DBLS + cc] = acc[i][j];
    }
  }
}

// ---------------- segmented selective scan: LDS-staged rows + PACKED f32 state math ----------------
// R15 structure (192-thread blocks, LDS double-buffered chunks, 3-deep u pipeline); step body
// restructured to float2 packed ops (v_pk_fma_f32/v_pk_mul_f32): h as f2[8], pw via r2/r4/r8
// broadcast tree (10 packed muls), h update 8 pk_mul + 8 pk_fma, y 8 pk_fma.
template<int PASS>
__global__ __launch_bounds__(192)
void k_scan(const float* __restrict__ x1c, const float* __restrict__ x2c,
            const float* __restrict__ dbl,
            const float* __restrict__ dtw, const float* __restrict__ dtb,
            const float* __restrict__ alogs, const float* __restrict__ dsv,
            float* __restrict__ hend, float* __restrict__ dsum,
            const float* __restrict__ hin, float* __restrict__ merged) {
  __shared__ float sd[2][CHS * DBLS];   // 2 x 640 floats = 5120 B
  int bid = blockIdx.x;          // SS*BKT
  int s  = bid & (SS - 1);
  int bk = bid >> 7;             // 0..15
  int b = bk >> 2, kdir = bk & 3;
  int c = threadIdx.x;           // 0..191
  int kc = kdir * CI + c;

  float w2r0 = dtw[kc * RR + 0], w2r1 = dtw[kc * RR + 1], w2r2 = dtw[kc * RR + 2];
  float w2r3 = dtw[kc * RR + 3], w2r4 = dtw[kc * RR + 4], w2r5 = dtw[kc * RR + 5];
  float bias = dtb[kc];
  float Dv   = (PASS == 2) ? dsv[kc] : 0.f;
  float Areg[NN];
#pragma unroll
  for (int n = 0; n < NN; n++) Areg[n] = -__expf(alogs[kc * NN + n]);
  float A1 = Areg[0];
  int ok = 1;
#pragma unroll
  for (int n = 1; n < NN; n++) {
    float want = A1 * (float)(n + 1);
    if (!(fabsf(Areg[n] - want) <= fabsf(want) * 1e-3f + 1e-6f)) ok = 0;
  }
  const bool structured = (__all(ok) != 0);   // A[n] = (n+1)*A1 -> dA[n] = r^(n+1)

  f2 h2[8];
  if (PASS == 2) {
    const f2* hb = (const f2*)(hin + ((size_t)(s * BKT + bk) * CI + c) * NN);
#pragma unroll
    for (int j = 0; j < 8; j++) h2[j] = hb[j];
  } else {
#pragma unroll
    for (int j = 0; j < 8; j++) h2[j] = f2{0.f, 0.f};
  }
  float dacc = 0.f;

  const float* dpf = dbl + (size_t)(bk * L2T + s * TT) * DBLS;   // block-uniform segment base
  const float* u1b = x1c + (size_t)b * LL * CI + c;
  const float* u2b = x2c + (size_t)b * LL * CI + c;

  auto spmap = [&](int l) -> int {
    int lt = (kdir >= 2) ? (LL - 1 - l) : l;
    return (kdir & 1) ? (((lt & 63) << 6) | (lt >> 6)) : lt;
  };

  // register-staged chunk load / LDS write (160 of 192 threads carry 16B each = 2560B)
  auto ldchunk = [&](int ch) -> float4 {
    if (threadIdx.x < 160)
      return *(const float4*)(dpf + ch * (CHS * DBLS) + threadIdx.x * 4);
    return float4{0.f, 0.f, 0.f, 0.f};
  };
  auto wrchunk = [&](int bufi, float4 v) {
    if (threadIdx.x < 160)
      *(float4*)&sd[bufi][threadIdx.x * 4] = v;
  };

  // one scan step; rowp points at the step's 40-float row in LDS (broadcast reads)
  auto step = [&](const float* rowp, float u, float& y) {
    f2 d01 = *(const f2*)(rowp + 0);
    f2 d23 = *(const f2*)(rowp + 2);
    f2 d45 = *(const f2*)(rowp + 4);
    const f2* B2 = (const f2*)(rowp + 6);
    const f2* C2 = (const f2*)(rowp + 22);
    float x = bias;
    x = fmaf(d01.x, w2r0, x); x = fmaf(d01.y, w2r1, x);
    x = fmaf(d23.x, w2r2, x); x = fmaf(d23.y, w2r3, x);
    x = fmaf(d45.x, w2r4, x); x = fmaf(d45.y, w2r5, x);
    float delta = (x > 15.f) ? x : __logf(1.f + __expf(x));
    float du = delta * u;
    f2 du2 = {du, du};
    f2 y2a = {0.f, 0.f}, y2b = {0.f, 0.f};
    if (structured) {
      float r  = __expf(delta * A1);
      float r2 = r * r;
      f2 rr  = {r, r2};
      f2 r2v = {r2, r2};
      f2 r4v = r2v * r2v;
      f2 r8v = r4v * r4v;
      f2 pw0 = rr;
      f2 pw1 = rr * r2v;
      f2 pw2 = rr * r4v;
      f2 pw3 = pw1 * r4v;
      f2 pw4 = rr * r8v;
      f2 pw5 = pw1 * r8v;
      f2 pw6 = pw2 * r8v;
      f2 pw7 = pw3 * r8v;
      h2[0] = fma2(h2[0], pw0, du2 * B2[0]);
      h2[1] = fma2(h2[1], pw1, du2 * B2[1]);
      h2[2] = fma2(h2[2], pw2, du2 * B2[2]);
      h2[3] = fma2(h2[3], pw3, du2 * B2[3]);
      h2[4] = fma2(h2[4], pw4, du2 * B2[4]);
      h2[5] = fma2(h2[5], pw5, du2 * B2[5]);
      h2[6] = fma2(h2[6], pw6, du2 * B2[6]);
      h2[7] = fma2(h2[7], pw7, du2 * B2[7]);
      if (PASS == 2) {
        y2a = fma2(h2[0], C2[0], y2a); y2b = fma2(h2[1], C2[1], y2b);
        y2a = fma2(h2[2], C2[2], y2a); y2b = fma2(h2[3], C2[3], y2b);
        y2a = fma2(h2[4], C2[4], y2a); y2b = fma2(h2[5], C2[5], y2b);
        y2a = fma2(h2[6], C2[6], y2a); y2b = fma2(h2[7], C2[7], y2b);
      }
    } else {
#pragma unroll
      for (int j = 0; j < 8; j++) {
        f2 dA2 = {__expf(delta * Areg[2 * j]), __expf(delta * Areg[2 * j + 1])};
        h2[j] = fma2(h2[j], dA2, du2 * B2[j]);
        if (PASS == 2) {
          if (j & 1) y2b = fma2(h2[j], C2[j], y2b);
          else       y2a = fma2(h2[j], C2[j], y2a);
        }
      }
    }
    if (PASS == 1) dacc += delta;
    else {
      f2 ys = y2a + y2b;
      y = fmaf(u, Dv, ys.x + ys.y);
    }
  };

  const int NP = TT / 2;         // pairs
  int l0 = (s * TT) >> 1;
  // u pipeline prologue (3 deep)
  int spC = spmap(l0);
  float u1C = u1b[(size_t)spC * CI];
  float u2C = u2b[(size_t)spC * CI];
  int spN = spmap(l0 + 1);
  float u1N = u1b[(size_t)spN * CI];
  float u2N = u2b[(size_t)spN * CI];
  int spN2 = spmap(l0 + 2);
  float u1N2 = u1b[(size_t)spN2 * CI];
  float u2N2 = u2b[(size_t)spN2 * CI];
  // LDS staging prologue: chunk0 written, chunk1 in flight
  float4 stg = ldchunk(0);
  wrchunk(0, stg);
  stg = ldchunk(1);
  __syncthreads();

#pragma unroll 1
  for (int ch = 0; ch < NCH; ch++) {
    const float* cb = sd[ch & 1];
#pragma unroll 1
    for (int pp = 0; pp < CHS / 2; pp++) {
      int p = (ch * CHS) / 2 + pp;
      const float* rA = &cb[(pp * 2) * DBLS];
      const float* rB = &cb[(pp * 2 + 1) * DBLS];
      int spN3 = 0; float u1N3 = 0.f, u2N3 = 0.f;
      if (p + 3 < NP) {
        spN3 = spmap(l0 + p + 3);
        u1N3 = u1b[(size_t)spN3 * CI];
        u2N3 = u2b[(size_t)spN3 * CI];
      }
      float ya, yb;
      step(rA, u1C, ya);                      // even step: modality rgb (m=0)
      step(rB, u2C, yb);                      // odd step: modality t (m=1)
      if (PASS == 2) {
        float* mrow = merged + (size_t)(b * LL + spC) * (2 * CI) + c;
        atomicAdd(mrow, ya);
        atomicAdd(mrow + CI, yb);
      }
      spC = spN;  u1C = u1N;  u2C = u2N;
      spN = spN2; u1N = u1N2; u2N = u2N2;
      spN2 = spN3; u1N2 = u1N3; u2N2 = u2N3;
    }
    if (ch + 1 < NCH) {
      wrchunk((ch + 1) & 1, stg);             // barrier-protected overwrite
      if (ch + 2 < NCH) stg = ldchunk(ch + 2);
      __syncthreads();
    }
  }

  if (PASS == 1) {
    f2* hb = (f2*)(hend + ((size_t)(s * BKT + bk) * CI + c) * NN);
#pragma unroll
    for (int j = 0; j < 8; j++) hb[j] = h2[j];
    dsum[(s * BKT + bk) * CI + c] = dacc;
  }
}

// ---------------- propagate segment initial states (two-buffer) ----------------
__global__ __launch_bounds__(256)
void k_prop(const float* __restrict__ hend, const float* __restrict__ dsum,
            const float* __restrict__ alogs, float* __restrict__ hin) {
  int idx = blockIdx.x * 256 + threadIdx.x;   // BKT*CI*NN = 49152
  int n = idx & 15;
  int rest = idx >> 4;
  int c = rest % CI;
  int bk = rest / CI;
  int k = bk & 3;
  float A = -__expf(alogs[(k * CI + c) * NN + n]);
  float h = 0.f;
  for (int s = 0; s < SS; s++) {
    int cell = (s * BKT + bk) * CI + c;
    hin[cell * NN + n] = h;
    float ap = __expf(A * dsum[cell]);
    h = h * ap + hend[cell * NN + n];
  }
}

// ---------------- LayerNorm over CI + SiLU(z) gate (in-place on merged) ----------------
__global__ __launch_bounds__(192)
void k_lngate(float* __restrict__ merged,
              const float* __restrict__ z1, const float* __restrict__ z2,
              const float* __restrict__ n1w, const float* __restrict__ n1b,
              const float* __restrict__ n2w, const float* __restrict__ n2b) {
  int bid = blockIdx.x;
  int m = bid & 1;
  int bl = bid >> 1;
  int c = threadIdx.x;
  float v = merged[(size_t)bid * CI + c];
  float s1 = v, s2 = v * v;
  for (int o = 32; o > 0; o >>= 1) {
    s1 += __shfl_xor(s1, o);
    s2 += __shfl_xor(s2, o);
  }
  __shared__ float red[2][3];
  int wv = threadIdx.x >> 6, ln = threadIdx.x & 63;
  if (ln == 0) { red[0][wv] = s1; red[1][wv] = s2; }
  __syncthreads();
  float S1 = red[0][0] + red[0][1] + red[0][2];
  float S2 = red[1][0] + red[1][1] + red[1][2];
  float mean = S1 * (1.f / CI);
  float var = S2 * (1.f / CI) - mean * mean;
  float rstd = rsqrtf(var + 1e-5f);
  const float* nw = m ? n2w : n1w;
  const float* nb = m ? n2b : n1b;
  float vn = (v - mean) * rstd * nw[c] + nb[c];
  float z = (m ? z2 : z1)[(size_t)bl * CI + c];
  float g = vn * (z / (1.f + __expf(-z)));
  merged[(size_t)bid * CI + c] = g;
}

// ---------------- out_proj: LDS-tiled GEMM. M=16384, N=96, K=192 (2 chunks) ----------------
__global__ __launch_bounds__(256)
void k_outproj(const float* __restrict__ g,
               const float* __restrict__ w1, const float* __restrict__ w2,
               float* __restrict__ out) {
  int mb = blockIdx.x;
  int m  = blockIdx.y;
  const float* w = m ? w2 : w1;
  __shared__ float As[64][100];
  __shared__ float Ws[96][98];
  int t = threadIdx.x;
  int tc = t & 15, tr = t >> 4;
  float acc[4][6] = {};
  for (int kc = 0; kc < 2; kc++) {
    if (kc) __syncthreads();
    for (int i = t; i < 1536; i += 256) {
      int r = i / 24, kk = (i % 24) * 4;
      *(float4*)&As[r][kk] =
          *(const float4*)&g[((size_t)(mb * 64 + r) * 2 + m) * CI + kc * 96 + kk];
    }
    for (int i = t; i < 4608; i += 256) {
      int r = i / 48, kk = (i % 48) * 2;
      *(float2*)&Ws[r][kk] = *(const float2*)&w[(size_t)r * CI + kc * 96 + kk];
    }
    __syncthreads();
    for (int k = 0; k < 96; k += 2) {
      float2 a[4], b[6];
#pragma unroll
      for (int i = 0; i < 4; i++) a[i] = *(const float2*)&As[tr * 4 + i][k];
#pragma unroll
      for (int j = 0; j < 6; j++) b[j] = *(const float2*)&Ws[tc * 6 + j][k];
#pragma unroll
      for (int i = 0; i < 4; i++)
#pragma unroll
        for (int j = 0; j < 6; j++) {
          acc[i][j] = fmaf(a[i].x, b[j].x, acc[i][j]);
          acc[i][j] = fmaf(a[i].y, b[j].y, acc[i][j]);
        }
    }
  }
  float* outp = out + (size_t)m * (BB * LL * DM);
#pragma unroll
  for (int i = 0; i < 4; i++) {
    size_t bl = (size_t)mb * 64 + tr * 4 + i;
#pragma unroll
    for (int j = 0; j < 6; j++)
      outp[bl * DM + tc * 6 + j] = acc[i][j];
  }
}

extern "C" void kernel_launch(void* const* d_in, const int* in_sizes, int n_in,
                              void* d_out, int out_size, void* d_ws, size_t ws_size,
                              hipStream_t stream) {
  const float* rgb = (const float*)d_in[0];
  const float* tin = (const float*)d_in[1];
  const float* ip1 = (const float*)d_in[2];
  const float* ip2 = (const float*)d_in[3];
  const float* c1w = (const float*)d_in[4];
  const float* c1b = (const float*)d_in[5];
  const float* c2w = (const float*)d_in[6];
  const float* c2b = (const float*)d_in[7];
  const float* wx  = (const float*)d_in[8];
  const float* dtw = (const float*)d_in[9];
  const float* dtb = (const float*)d_in[10];
  const float* alg = (const float*)d_in[11];
  const float* Dsp = (const float*)d_in[12];
  const float* n1w = (const float*)d_in[13];
  const float* n1b = (const float*)d_in[14];
  const float* n2w = (const float*)d_in[15];
  const float* n2b = (const float*)d_in[16];
  const float* op1 = (const float*)d_in[17];
  const float* op2 = (const float*)d_in[18];

  float* ws = (float*)d_ws;
  float* xp1 = ws + OFF_XPRE1;
  float* xp2 = ws + OFF_XPRE2;
  float* z1  = ws + OFF_Z1;
  float* z2  = ws + OFF_Z2;
  float* x1c = ws + OFF_X1C;
  float* x2c = ws + OFF_X2C;
  float* dbl = ws + OFF_DBL;
  float* mg  = ws + OFF_MERG;
  float* dsm = ws + OFF_DSUM;
  // hend lives in the mg region (pass1 -> prop only; memset erases it afterwards).
  // hin spans xp1+xp2 (dead after k_conv): SS*BKT*CI*NN = 6291456 floats, exact fit.
  float* he  = ws + OFF_MERG;
  float* hi  = ws + OFF_XPRE1;
  float* out = (float*)d_out;

  k_inproj<<<dim3(256, 4, 2), 256, 0, stream>>>(rgb, tin, ip1, ip2, xp1, xp2, z1, z2);
  k_conv<<<dim3(12288, 2), 256, 0, stream>>>(xp1, xp2, c1w, c1b, c2w, c2b, x1c, x2c);
  k_dbl<<<dim3(128, 16), 256, 0, stream>>>(x1c, x2c, wx, dbl);
  k_scan<1><<<SS * BKT, 192, 0, stream>>>(x1c, x2c, dbl, dtw, dtb, alg, Dsp, he, dsm, hi, mg);
  k_prop<<<192, 256, 0, stream>>>(he, dsm, alg, hi);
  // zero the merge accumulator only now (hend is dead after k_prop)
  hipMemsetAsync(mg, 0, (size_t)6291456 * sizeof(float), stream);
  k_scan<2><<<SS * BKT, 192, 0, stream>>>(x1c, x2c, dbl, dtw, dtb, alg, Dsp, he, dsm, hi, mg);
  k_lngate<<<BB * LL * 2, 192, 0, stream>>>(mg, z1, z2, n1w, n1b, n2w, n2b);
  k_outproj<<<dim3(256, 2), 256, 0, stream>>>(mg, op1, op2, out);
}

// Round 17
// 403.321 us; speedup vs baseline: 1.1051x; 1.0362x over previous
//
#include <hip/hip_runtime.h>
#include <math.h>

// Problem constants
#define BB   4
#define LL   4096          // H*W
#define L2T  8192          // 2*L (modality-interleaved sequence)
#define DM   96            // D_MODEL
#define CI   192           // D_INNER
#define KD   4             // K directions
#define NN   16            // D_STATE
#define RR   6             // DT_RANK
#define BKT  16            // B*K
#define SS   128           // scan segments
#define TT   64            // steps per segment = L2T/SS
#define DBLS 40            // padded row stride for x_dbl (38 -> 40 for float4)
#define CHS  16            // steps per LDS-staged chunk
#define NCH  (TT / CHS)    // 4 chunks per segment

// Workspace layout (float offsets) — identical to R9/R11/R13/R15/R16 (proven)
#define OFF_XPRE1 0
#define OFF_XPRE2 3145728
#define OFF_Z1    6291456
#define OFF_Z2    9437184
#define OFF_X1C   12582912
#define OFF_X2C   15728640
#define OFF_DBL   18874368   // BKT*L2T*40 = 5242880
#define OFF_MERG  24117248   // B*L*2*CI = 6291456 == SS*BKT*CI*NN (hend fits exactly)
#define OFF_DSUM  30408704   // SS*BKT*CI = 393216

typedef float f2 __attribute__((ext_vector_type(2)));
static __device__ __forceinline__ f2 fma2(f2 a, f2 b, f2 c) {
  return __builtin_elementwise_fma(a, b, c);
}

// ---------------- in_proj: LDS-tiled GEMM. M=16384, N=384 (4 tiles of 96), K=96 ----------------
__global__ __launch_bounds__(256)
void k_inproj(const float* __restrict__ rgb, const float* __restrict__ tin,
              const float* __restrict__ w1, const float* __restrict__ w2,
              float* __restrict__ xp1, float* __restrict__ xp2,
              float* __restrict__ zz1, float* __restrict__ zz2) {
  int mb = blockIdx.x;     // row tile
  int nb = blockIdx.y;     // col tile (0..3)
  int m  = blockIdx.z;     // modality
  const float* in = m ? tin : rgb;
  const float* w  = (m ? w2 : w1) + nb * 96 * DM;
  __shared__ float As[64][100];
  __shared__ float Ws[96][98];
  int t = threadIdx.x;
  const float4* asrc = (const float4*)(in + (size_t)mb * 64 * DM);
  for (int i = t; i < 1536; i += 256) {
    int r = i / 24, kk = (i % 24) * 4;
    *(float4*)&As[r][kk] = asrc[i];
  }
  const float2* wsrc = (const float2*)w;
  for (int i = t; i < 4608; i += 256) {
    int r = i / 48, kk = (i % 48) * 2;
    *(float2*)&Ws[r][kk] = wsrc[i];
  }
  __syncthreads();
  int tc = t & 15, tr = t >> 4;
  float acc[4][6] = {};
  for (int k = 0; k < 96; k += 2) {
    float2 a[4], b[6];
#pragma unroll
    for (int i = 0; i < 4; i++) a[i] = *(const float2*)&As[tr * 4 + i][k];
#pragma unroll
    for (int j = 0; j < 6; j++) b[j] = *(const float2*)&Ws[tc * 6 + j][k];
#pragma unroll
    for (int i = 0; i < 4; i++)
#pragma unroll
      for (int j = 0; j < 6; j++) {
        acc[i][j] = fmaf(a[i].x, b[j].x, acc[i][j]);
        acc[i][j] = fmaf(a[i].y, b[j].y, acc[i][j]);
      }
  }
  float* dst = (nb < 2) ? (m ? xp2 : xp1) : (m ? zz2 : zz1);
  int colbase = (nb & 1) * 96 + tc * 6;
#pragma unroll
  for (int i = 0; i < 4; i++) {
    size_t bl = (size_t)mb * 64 + tr * 4 + i;
#pragma unroll
    for (int j = 0; j < 6; j++)
      dst[bl * CI + colbase + j] = acc[i][j];
  }
}

// ---------------- depthwise 3x3 conv (SAME, zero pad) + bias + SiLU ----------------
__global__ __launch_bounds__(256)
void k_conv(const float* __restrict__ xp1, const float* __restrict__ xp2,
            const float* __restrict__ c1w, const float* __restrict__ c1b,
            const float* __restrict__ c2w, const float* __restrict__ c2b,
            float* __restrict__ o1, float* __restrict__ o2) {
  int m = blockIdx.y;
  const float* in = m ? xp2 : xp1;
  const float* cw = m ? c2w : c1w;
  const float* cb = m ? c2b : c1b;
  float* out = m ? o2 : o1;
  int idx = blockIdx.x * 256 + threadIdx.x;
  int c = idx % CI;
  int bl = idx / CI;
  int b = bl / LL, l = bl % LL;
  int hh = l >> 6, ww = l & 63;
  float a = cb[c];
#pragma unroll
  for (int di = 0; di < 3; di++) {
    int h2 = hh + di - 1;
    if ((unsigned)h2 >= 64u) continue;
#pragma unroll
    for (int dj = 0; dj < 3; dj++) {
      int w2 = ww + dj - 1;
      if ((unsigned)w2 >= 64u) continue;
      a = fmaf(in[(b * LL + h2 * 64 + w2) * CI + c], cw[c * 9 + di * 3 + dj], a);
    }
  }
  out[idx] = a / (1.f + __expf(-a));
}

// ---------------- x_dbl projection as tiled GEMM per (b,k) ----------------
__global__ __launch_bounds__(256)
void k_dbl(const float* __restrict__ x1c, const float* __restrict__ x2c,
           const float* __restrict__ wx, float* __restrict__ dbl) {
  int pt = blockIdx.x;
  int bk = blockIdx.y;
  int b = bk >> 2, k = bk & 3;
  __shared__ float As[64][100];
  __shared__ float Ws[40][100];
  int t = threadIdx.x;
  int tc = t & 7, tr = t >> 3;
  float acc[2][5] = {};
  for (int kc = 0; kc < 2; kc++) {
    if (kc) __syncthreads();
    for (int i = t; i < 1536; i += 256) {
      int r = i / 24, kk = (i % 24) * 4;
      int l2 = pt * 64 + r;
      int mm = l2 & 1, l = l2 >> 1;
      int lt = (k >= 2) ? (LL - 1 - l) : l;
      int sp = (k & 1) ? (((lt & 63) << 6) | (lt >> 6)) : lt;
      const float* src = (mm ? x2c : x1c) + ((size_t)(b * LL + sp)) * CI + kc * 96;
      *(float4*)&As[r][kk] = *(const float4*)(src + kk);
    }
    for (int i = t; i < 960; i += 256) {
      int r = i / 24, kk = (i % 24) * 4;
      float4 v;
      if (r < 38) v = *(const float4*)&wx[(size_t)(k * 38 + r) * CI + kc * 96 + kk];
      else        v = float4{0.f, 0.f, 0.f, 0.f};
      *(float4*)&Ws[r][kk] = v;
    }
    __syncthreads();
    for (int kk2 = 0; kk2 < 96; kk2 += 2) {
      float2 a[2], bv[5];
#pragma unroll
      for (int i = 0; i < 2; i++) a[i] = *(const float2*)&As[tr * 2 + i][kk2];
#pragma unroll
      for (int j = 0; j < 5; j++) bv[j] = *(const float2*)&Ws[tc * 5 + j][kk2];
#pragma unroll
      for (int i = 0; i < 2; i++)
#pragma unroll
        for (int j = 0; j < 5; j++) {
          acc[i][j] = fmaf(a[i].x, bv[j].x, acc[i][j]);
          acc[i][j] = fmaf(a[i].y, bv[j].y, acc[i][j]);
        }
    }
  }
#pragma unroll
  for (int i = 0; i < 2; i++) {
    size_t row = (size_t)bk * L2T + pt * 64 + tr * 2 + i;
#pragma unroll
    for (int j = 0; j < 5; j++) {
      int cc = tc * 5 + j;
      if (cc < 38) dbl[row * DBLS + cc] = acc[i][j];
    }
  }
}

// ---------------- segmented selective scan: LDS-staged rows + PACKED f32 state math (R16, unchanged) ----
template<int PASS>
__global__ __launch_bounds__(192)
void k_scan(const float* __restrict__ x1c, const float* __restrict__ x2c,
            const float* __restrict__ dbl,
            const float* __restrict__ dtw, const float* __restrict__ dtb,
            const float* __restrict__ alogs, const float* __restrict__ dsv,
            float* __restrict__ hend, float* __restrict__ dsum,
            const float* __restrict__ hin, float* __restrict__ merged) {
  __shared__ float sd[2][CHS * DBLS];   // 2 x 640 floats = 5120 B
  int bid = blockIdx.x;          // SS*BKT
  int s  = bid & (SS - 1);
  int bk = bid >> 7;             // 0..15
  int b = bk >> 2, kdir = bk & 3;
  int c = threadIdx.x;           // 0..191
  int kc = kdir * CI + c;

  float w2r0 = dtw[kc * RR + 0], w2r1 = dtw[kc * RR + 1], w2r2 = dtw[kc * RR + 2];
  float w2r3 = dtw[kc * RR + 3], w2r4 = dtw[kc * RR + 4], w2r5 = dtw[kc * RR + 5];
  float bias = dtb[kc];
  float Dv   = (PASS == 2) ? dsv[kc] : 0.f;
  float Areg[NN];
#pragma unroll
  for (int n = 0; n < NN; n++) Areg[n] = -__expf(alogs[kc * NN + n]);
  float A1 = Areg[0];
  int ok = 1;
#pragma unroll
  for (int n = 1; n < NN; n++) {
    float want = A1 * (float)(n + 1);
    if (!(fabsf(Areg[n] - want) <= fabsf(want) * 1e-3f + 1e-6f)) ok = 0;
  }
  const bool structured = (__all(ok) != 0);   // A[n] = (n+1)*A1 -> dA[n] = r^(n+1)

  f2 h2[8];
  if (PASS == 2) {
    const f2* hb = (const f2*)(hin + ((size_t)(s * BKT + bk) * CI + c) * NN);
#pragma unroll
    for (int j = 0; j < 8; j++) h2[j] = hb[j];
  } else {
#pragma unroll
    for (int j = 0; j < 8; j++) h2[j] = f2{0.f, 0.f};
  }
  float dacc = 0.f;

  const float* dpf = dbl + (size_t)(bk * L2T + s * TT) * DBLS;   // block-uniform segment base
  const float* u1b = x1c + (size_t)b * LL * CI + c;
  const float* u2b = x2c + (size_t)b * LL * CI + c;

  auto spmap = [&](int l) -> int {
    int lt = (kdir >= 2) ? (LL - 1 - l) : l;
    return (kdir & 1) ? (((lt & 63) << 6) | (lt >> 6)) : lt;
  };

  auto ldchunk = [&](int ch) -> float4 {
    if (threadIdx.x < 160)
      return *(const float4*)(dpf + ch * (CHS * DBLS) + threadIdx.x * 4);
    return float4{0.f, 0.f, 0.f, 0.f};
  };
  auto wrchunk = [&](int bufi, float4 v) {
    if (threadIdx.x < 160)
      *(float4*)&sd[bufi][threadIdx.x * 4] = v;
  };

  auto step = [&](const float* rowp, float u, float& y) {
    f2 d01 = *(const f2*)(rowp + 0);
    f2 d23 = *(const f2*)(rowp + 2);
    f2 d45 = *(const f2*)(rowp + 4);
    const f2* B2 = (const f2*)(rowp + 6);
    const f2* C2 = (const f2*)(rowp + 22);
    float x = bias;
    x = fmaf(d01.x, w2r0, x); x = fmaf(d01.y, w2r1, x);
    x = fmaf(d23.x, w2r2, x); x = fmaf(d23.y, w2r3, x);
    x = fmaf(d45.x, w2r4, x); x = fmaf(d45.y, w2r5, x);
    float delta = (x > 15.f) ? x : __logf(1.f + __expf(x));
    float du = delta * u;
    f2 du2 = {du, du};
    f2 y2a = {0.f, 0.f}, y2b = {0.f, 0.f};
    if (structured) {
      float r  = __expf(delta * A1);
      float r2 = r * r;
      f2 rr  = {r, r2};
      f2 r2v = {r2, r2};
      f2 r4v = r2v * r2v;
      f2 r8v = r4v * r4v;
      f2 pw0 = rr;
      f2 pw1 = rr * r2v;
      f2 pw2 = rr * r4v;
      f2 pw3 = pw1 * r4v;
      f2 pw4 = rr * r8v;
      f2 pw5 = pw1 * r8v;
      f2 pw6 = pw2 * r8v;
      f2 pw7 = pw3 * r8v;
      h2[0] = fma2(h2[0], pw0, du2 * B2[0]);
      h2[1] = fma2(h2[1], pw1, du2 * B2[1]);
      h2[2] = fma2(h2[2], pw2, du2 * B2[2]);
      h2[3] = fma2(h2[3], pw3, du2 * B2[3]);
      h2[4] = fma2(h2[4], pw4, du2 * B2[4]);
      h2[5] = fma2(h2[5], pw5, du2 * B2[5]);
      h2[6] = fma2(h2[6], pw6, du2 * B2[6]);
      h2[7] = fma2(h2[7], pw7, du2 * B2[7]);
      if (PASS == 2) {
        y2a = fma2(h2[0], C2[0], y2a); y2b = fma2(h2[1], C2[1], y2b);
        y2a = fma2(h2[2], C2[2], y2a); y2b = fma2(h2[3], C2[3], y2b);
        y2a = fma2(h2[4], C2[4], y2a); y2b = fma2(h2[5], C2[5], y2b);
        y2a = fma2(h2[6], C2[6], y2a); y2b = fma2(h2[7], C2[7], y2b);
      }
    } else {
#pragma unroll
      for (int j = 0; j < 8; j++) {
        f2 dA2 = {__expf(delta * Areg[2 * j]), __expf(delta * Areg[2 * j + 1])};
        h2[j] = fma2(h2[j], dA2, du2 * B2[j]);
        if (PASS == 2) {
          if (j & 1) y2b = fma2(h2[j], C2[j], y2b);
          else       y2a = fma2(h2[j], C2[j], y2a);
        }
      }
    }
    if (PASS == 1) dacc += delta;
    else {
      f2 ys = y2a + y2b;
      y = fmaf(u, Dv, ys.x + ys.y);
    }
  };

  const int NP = TT / 2;         // pairs
  int l0 = (s * TT) >> 1;
  int spC = spmap(l0);
  float u1C = u1b[(size_t)spC * CI];
  float u2C = u2b[(size_t)spC * CI];
  int spN = spmap(l0 + 1);
  float u1N = u1b[(size_t)spN * CI];
  float u2N = u2b[(size_t)spN * CI];
  int spN2 = spmap(l0 + 2);
  float u1N2 = u1b[(size_t)spN2 * CI];
  float u2N2 = u2b[(size_t)spN2 * CI];
  float4 stg = ldchunk(0);
  wrchunk(0, stg);
  stg = ldchunk(1);
  __syncthreads();

#pragma unroll 1
  for (int ch = 0; ch < NCH; ch++) {
    const float* cb = sd[ch & 1];
#pragma unroll 1
    for (int pp = 0; pp < CHS / 2; pp++) {
      int p = (ch * CHS) / 2 + pp;
      const float* rA = &cb[(pp * 2) * DBLS];
      const float* rB = &cb[(pp * 2 + 1) * DBLS];
      int spN3 = 0; float u1N3 = 0.f, u2N3 = 0.f;
      if (p + 3 < NP) {
        spN3 = spmap(l0 + p + 3);
        u1N3 = u1b[(size_t)spN3 * CI];
        u2N3 = u2b[(size_t)spN3 * CI];
      }
      float ya, yb;
      step(rA, u1C, ya);                      // even step: modality rgb (m=0)
      step(rB, u2C, yb);                      // odd step: modality t (m=1)
      if (PASS == 2) {
        float* mrow = merged + (size_t)(b * LL + spC) * (2 * CI) + c;
        atomicAdd(mrow, ya);
        atomicAdd(mrow + CI, yb);
      }
      spC = spN;  u1C = u1N;  u2C = u2N;
      spN = spN2; u1N = u1N2; u2N = u2N2;
      spN2 = spN3; u1N2 = u1N3; u2N2 = u2N3;
    }
    if (ch + 1 < NCH) {
      wrchunk((ch + 1) & 1, stg);             // barrier-protected overwrite
      if (ch + 2 < NCH) stg = ldchunk(ch + 2);
      __syncthreads();
    }
  }

  if (PASS == 1) {
    f2* hb = (f2*)(hend + ((size_t)(s * BKT + bk) * CI + c) * NN);
#pragma unroll
    for (int j = 0; j < 8; j++) hb[j] = h2[j];
    dsum[(s * BKT + bk) * CI + c] = dacc;
  }
}

// ---------------- propagate segment initial states (two-buffer) ----------------
__global__ __launch_bounds__(256)
void k_prop(const float* __restrict__ hend, const float* __restrict__ dsum,
            const float* __restrict__ alogs, float* __restrict__ hin) {
  int idx = blockIdx.x * 256 + threadIdx.x;   // BKT*CI*NN = 49152
  int n = idx & 15;
  int rest = idx >> 4;
  int c = rest % CI;
  int bk = rest / CI;
  int k = bk & 3;
  float A = -__expf(alogs[(k * CI + c) * NN + n]);
  float h = 0.f;
  for (int s = 0; s < SS; s++) {
    int cell = (s * BKT + bk) * CI + c;
    hin[cell * NN + n] = h;
    float ap = __expf(A * dsum[cell]);
    h = h * ap + hend[cell * NN + n];
  }
}

// ---------------- out_proj FUSED with LayerNorm + SiLU(z) gate ----------------
// Per block (mb, m): Phase A computes per-row mean/rstd for its 64 merged-rows (4 threads/row,
// intra-wave shfl reduce). Staging then applies LN + gate inline before the GEMM. k_lngate gone.
__global__ __launch_bounds__(256)
void k_outproj(const float* __restrict__ g,
               const float* __restrict__ z1, const float* __restrict__ z2,
               const float* __restrict__ n1w, const float* __restrict__ n1b,
               const float* __restrict__ n2w, const float* __restrict__ n2b,
               const float* __restrict__ w1, const float* __restrict__ w2,
               float* __restrict__ out) {
  int mb = blockIdx.x;
  int m  = blockIdx.y;
  const float* w = m ? w2 : w1;
  const float* nw = m ? n2w : n1w;
  const float* nb = m ? n2b : n1b;
  const float* zz = m ? z2 : z1;
  __shared__ float As[64][100];
  __shared__ float Ws[96][98];
  __shared__ float st[64][2];    // mean, rstd per row
  int t = threadIdx.x;

  // Phase A: row statistics
  {
    int r = t >> 2, q = t & 3;
    const float4* grow = (const float4*)(g + ((size_t)(mb * 64 + r) * 2 + m) * CI + q * 48);
    float s1 = 0.f, s2 = 0.f;
#pragma unroll
    for (int i = 0; i < 12; i++) {
      float4 v = grow[i];
      s1 += (v.x + v.y) + (v.z + v.w);
      s2 += (v.x * v.x + v.y * v.y) + (v.z * v.z + v.w * v.w);
    }
    s1 += __shfl_xor(s1, 1); s2 += __shfl_xor(s2, 1);
    s1 += __shfl_xor(s1, 2); s2 += __shfl_xor(s2, 2);
    if (q == 0) {
      float mean = s1 * (1.f / CI);
      float var = s2 * (1.f / CI) - mean * mean;
      st[r][0] = mean;
      st[r][1] = rsqrtf(var + 1e-5f);
    }
  }
  __syncthreads();

  int tc = t & 15, tr = t >> 4;
  float acc[4][6] = {};
  for (int kc = 0; kc < 2; kc++) {
    if (kc) __syncthreads();
    for (int i = t; i < 1536; i += 256) {
      int r = i / 24, kk = (i % 24) * 4;
      int cc = kc * 96 + kk;
      float4 gv = *(const float4*)&g[((size_t)(mb * 64 + r) * 2 + m) * CI + cc];
      float4 zv = *(const float4*)&zz[(size_t)(mb * 64 + r) * CI + cc];
      float4 wv = *(const float4*)&nw[cc];
      float4 bv = *(const float4*)&nb[cc];
      float mean = st[r][0], rstd = st[r][1];
      float4 o;
      o.x = ((gv.x - mean) * rstd * wv.x + bv.x) * (zv.x / (1.f + __expf(-zv.x)));
      o.y = ((gv.y - mean) * rstd * wv.y + bv.y) * (zv.y / (1.f + __expf(-zv.y)));
      o.z = ((gv.z - mean) * rstd * wv.z + bv.z) * (zv.z / (1.f + __expf(-zv.z)));
      o.w = ((gv.w - mean) * rstd * wv.w + bv.w) * (zv.w / (1.f + __expf(-zv.w)));
      *(float4*)&As[r][kk] = o;
    }
    for (int i = t; i < 4608; i += 256) {
      int r = i / 48, kk = (i % 48) * 2;
      *(float2*)&Ws[r][kk] = *(const float2*)&w[(size_t)r * CI + kc * 96 + kk];
    }
    __syncthreads();
    for (int k = 0; k < 96; k += 2) {
      float2 a[4], b[6];
#pragma unroll
      for (int i = 0; i < 4; i++) a[i] = *(const float2*)&As[tr * 4 + i][k];
#pragma unroll
      for (int j = 0; j < 6; j++) b[j] = *(const float2*)&Ws[tc * 6 + j][k];
#pragma unroll
      for (int i = 0; i < 4; i++)
#pragma unroll
        for (int j = 0; j < 6; j++) {
          acc[i][j] = fmaf(a[i].x, b[j].x, acc[i][j]);
          acc[i][j] = fmaf(a[i].y, b[j].y, acc[i][j]);
        }
    }
  }
  float* outp = out + (size_t)m * (BB * LL * DM);
#pragma unroll
  for (int i = 0; i < 4; i++) {
    size_t bl = (size_t)mb * 64 + tr * 4 + i;
#pragma unroll
    for (int j = 0; j < 6; j++)
      outp[bl * DM + tc * 6 + j] = acc[i][j];
  }
}

extern "C" void kernel_launch(void* const* d_in, const int* in_sizes, int n_in,
                              void* d_out, int out_size, void* d_ws, size_t ws_size,
                              hipStream_t stream) {
  const float* rgb = (const float*)d_in[0];
  const float* tin = (const float*)d_in[1];
  const float* ip1 = (const float*)d_in[2];
  const float* ip2 = (const float*)d_in[3];
  const float* c1w = (const float*)d_in[4];
  const float* c1b = (const float*)d_in[5];
  const float* c2w = (const float*)d_in[6];
  const float* c2b = (const float*)d_in[7];
  const float* wx  = (const float*)d_in[8];
  const float* dtw = (const float*)d_in[9];
  const float* dtb = (const float*)d_in[10];
  const float* alg = (const float*)d_in[11];
  const float* Dsp = (const float*)d_in[12];
  const float* n1w = (const float*)d_in[13];
  const float* n1b = (const float*)d_in[14];
  const float* n2w = (const float*)d_in[15];
  const float* n2b = (const float*)d_in[16];
  const float* op1 = (const float*)d_in[17];
  const float* op2 = (const float*)d_in[18];

  float* ws = (float*)d_ws;
  float* xp1 = ws + OFF_XPRE1;
  float* xp2 = ws + OFF_XPRE2;
  float* z1  = ws + OFF_Z1;
  float* z2  = ws + OFF_Z2;
  float* x1c = ws + OFF_X1C;
  float* x2c = ws + OFF_X2C;
  float* dbl = ws + OFF_DBL;
  float* mg  = ws + OFF_MERG;
  float* dsm = ws + OFF_DSUM;
  // hend lives in the mg region (pass1 -> prop only; memset erases it afterwards).
  // hin spans xp1+xp2 (dead after k_conv): SS*BKT*CI*NN = 6291456 floats, exact fit.
  float* he  = ws + OFF_MERG;
  float* hi  = ws + OFF_XPRE1;
  float* out = (float*)d_out;

  k_inproj<<<dim3(256, 4, 2), 256, 0, stream>>>(rgb, tin, ip1, ip2, xp1, xp2, z1, z2);
  k_conv<<<dim3(12288, 2), 256, 0, stream>>>(xp1, xp2, c1w, c1b, c2w, c2b, x1c, x2c);
  k_dbl<<<dim3(128, 16), 256, 0, stream>>>(x1c, x2c, wx, dbl);
  k_scan<1><<<SS * BKT, 192, 0, stream>>>(x1c, x2c, dbl, dtw, dtb, alg, Dsp, he, dsm, hi, mg);
  k_prop<<<192, 256, 0, stream>>>(he, dsm, alg, hi);
  // zero the merge accumulator only now (hend is dead after k_prop)
  hipMemsetAsync(mg, 0, (size_t)6291456 * sizeof(float), stream);
  k_scan<2><<<SS * BKT, 192, 0, stream>>>(x1c, x2c, dbl, dtw, dtb, alg, Dsp, he, dsm, hi, mg);
  k_outproj<<<dim3(256, 2), 256, 0, stream>>>(mg, z1, z2, n1w, n1b, n2w, n2b, op1, op2, out);
}

// Round 18
// 393.909 us; speedup vs baseline: 1.1315x; 1.0239x over previous
//
#include <hip/hip_runtime.h>
#include <math.h>

// Problem constants
#define BB   4
#define LL   4096          // H*W
#define L2T  8192          // 2*L (modality-interleaved sequence)
#define DM   96            // D_MODEL
#define CI   192           // D_INNER
#define KD   4             // K directions
#define NN   16            // D_STATE
#define RR   6             // DT_RANK
#define BKT  16            // B*K
#define SS   128           // scan segments
#define TT   64            // steps per segment = L2T/SS
#define DBLS 40            // padded row stride for x_dbl (38 -> 40 for float4)
#define CHS  16            // steps per LDS-staged chunk
#define NCH  (TT / CHS)    // 4 chunks per segment

// Workspace layout (float offsets) — identical to R9..R17 (proven)
#define OFF_XPRE1 0
#define OFF_XPRE2 3145728
#define OFF_Z1    6291456
#define OFF_Z2    9437184
#define OFF_X1C   12582912
#define OFF_X2C   15728640
#define OFF_DBL   18874368   // BKT*L2T*40 = 5242880
#define OFF_MERG  24117248   // B*L*2*CI = 6291456 == SS*BKT*CI*NN (hend fits exactly)
#define OFF_DSUM  30408704   // SS*BKT*CI = 393216

typedef float f2 __attribute__((ext_vector_type(2)));
typedef float f4v __attribute__((ext_vector_type(4)));
static __device__ __forceinline__ f2 fma2(f2 a, f2 b, f2 c) {
  return __builtin_elementwise_fma(a, b, c);
}
#define LO2(q) __builtin_shufflevector(q, q, 0, 1)
#define HI2(q) __builtin_shufflevector(q, q, 2, 3)

// ---------------- in_proj: LDS-tiled GEMM. M=16384, N=384 (4 tiles of 96), K=96 ----------------
__global__ __launch_bounds__(256)
void k_inproj(const float* __restrict__ rgb, const float* __restrict__ tin,
              const float* __restrict__ w1, const float* __restrict__ w2,
              float* __restrict__ xp1, float* __restrict__ xp2,
              float* __restrict__ zz1, float* __restrict__ zz2) {
  int mb = blockIdx.x;     // row tile
  int nb = blockIdx.y;     // col tile (0..3)
  int m  = blockIdx.z;     // modality
  const float* in = m ? tin : rgb;
  const float* w  = (m ? w2 : w1) + nb * 96 * DM;
  __shared__ float As[64][100];
  __shared__ float Ws[96][98];
  int t = threadIdx.x;
  const float4* asrc = (const float4*)(in + (size_t)mb * 64 * DM);
  for (int i = t; i < 1536; i += 256) {
    int r = i / 24, kk = (i % 24) * 4;
    *(float4*)&As[r][kk] = asrc[i];
  }
  const float2* wsrc = (const float2*)w;
  for (int i = t; i < 4608; i += 256) {
    int r = i / 48, kk = (i % 48) * 2;
    *(float2*)&Ws[r][kk] = wsrc[i];
  }
  __syncthreads();
  int tc = t & 15, tr = t >> 4;
  float acc[4][6] = {};
  for (int k = 0; k < 96; k += 2) {
    float2 a[4], b[6];
#pragma unroll
    for (int i = 0; i < 4; i++) a[i] = *(const float2*)&As[tr * 4 + i][k];
#pragma unroll
    for (int j = 0; j < 6; j++) b[j] = *(const float2*)&Ws[tc * 6 + j][k];
#pragma unroll
    for (int i = 0; i < 4; i++)
#pragma unroll
      for (int j = 0; j < 6; j++) {
        acc[i][j] = fmaf(a[i].x, b[j].x, acc[i][j]);
        acc[i][j] = fmaf(a[i].y, b[j].y, acc[i][j]);
      }
  }
  float* dst = (nb < 2) ? (m ? xp2 : xp1) : (m ? zz2 : zz1);
  int colbase = (nb & 1) * 96 + tc * 6;
#pragma unroll
  for (int i = 0; i < 4; i++) {
    size_t bl = (size_t)mb * 64 + tr * 4 + i;
#pragma unroll
    for (int j = 0; j < 6; j++)
      dst[bl * CI + colbase + j] = acc[i][j];
  }
}

// ---------------- depthwise 3x3 conv (SAME, zero pad) + bias + SiLU ----------------
__global__ __launch_bounds__(256)
void k_conv(const float* __restrict__ xp1, const float* __restrict__ xp2,
            const float* __restrict__ c1w, const float* __restrict__ c1b,
            const float* __restrict__ c2w, const float* __restrict__ c2b,
            float* __restrict__ o1, float* __restrict__ o2) {
  int m = blockIdx.y;
  const float* in = m ? xp2 : xp1;
  const float* cw = m ? c2w : c1w;
  const float* cb = m ? c2b : c1b;
  float* out = m ? o2 : o1;
  int idx = blockIdx.x * 256 + threadIdx.x;
  int c = idx % CI;
  int bl = idx / CI;
  int b = bl / LL, l = bl % LL;
  int hh = l >> 6, ww = l & 63;
  float a = cb[c];
#pragma unroll
  for (int di = 0; di < 3; di++) {
    int h2 = hh + di - 1;
    if ((unsigned)h2 >= 64u) continue;
#pragma unroll
    for (int dj = 0; dj < 3; dj++) {
      int w2 = ww + dj - 1;
      if ((unsigned)w2 >= 64u) continue;
      a = fmaf(in[(b * LL + h2 * 64 + w2) * CI + c], cw[c * 9 + di * 3 + dj], a);
    }
  }
  out[idx] = a / (1.f + __expf(-a));
}

// ---------------- x_dbl projection as tiled GEMM per (b,k) ----------------
__global__ __launch_bounds__(256)
void k_dbl(const float* __restrict__ x1c, const float* __restrict__ x2c,
           const float* __restrict__ wx, float* __restrict__ dbl) {
  int pt = blockIdx.x;
  int bk = blockIdx.y;
  int b = bk >> 2, k = bk & 3;
  __shared__ float As[64][100];
  __shared__ float Ws[40][100];
  int t = threadIdx.x;
  int tc = t & 7, tr = t >> 3;
  float acc[2][5] = {};
  for (int kc = 0; kc < 2; kc++) {
    if (kc) __syncthreads();
    for (int i = t; i < 1536; i += 256) {
      int r = i / 24, kk = (i % 24) * 4;
      int l2 = pt * 64 + r;
      int mm = l2 & 1, l = l2 >> 1;
      int lt = (k >= 2) ? (LL - 1 - l) : l;
      int sp = (k & 1) ? (((lt & 63) << 6) | (lt >> 6)) : lt;
      const float* src = (mm ? x2c : x1c) + ((size_t)(b * LL + sp)) * CI + kc * 96;
      *(float4*)&As[r][kk] = *(const float4*)(src + kk);
    }
    for (int i = t; i < 960; i += 256) {
      int r = i / 24, kk = (i % 24) * 4;
      float4 v;
      if (r < 38) v = *(const float4*)&wx[(size_t)(k * 38 + r) * CI + kc * 96 + kk];
      else        v = float4{0.f, 0.f, 0.f, 0.f};
      *(float4*)&Ws[r][kk] = v;
    }
    __syncthreads();
    for (int kk2 = 0; kk2 < 96; kk2 += 2) {
      float2 a[2], bv[5];
#pragma unroll
      for (int i = 0; i < 2; i++) a[i] = *(const float2*)&As[tr * 2 + i][kk2];
#pragma unroll
      for (int j = 0; j < 5; j++) bv[j] = *(const float2*)&Ws[tc * 5 + j][kk2];
#pragma unroll
      for (int i = 0; i < 2; i++)
#pragma unroll
        for (int j = 0; j < 5; j++) {
          acc[i][j] = fmaf(a[i].x, bv[j].x, acc[i][j]);
          acc[i][j] = fmaf(a[i].y, bv[j].y, acc[i][j]);
        }
    }
  }
#pragma unroll
  for (int i = 0; i < 2; i++) {
    size_t row = (size_t)bk * L2T + pt * 64 + tr * 2 + i;
#pragma unroll
    for (int j = 0; j < 5; j++) {
      int cc = tc * 5 + j;
      if (cc < 38) dbl[row * DBLS + cc] = acc[i][j];
    }
  }
}

// ---------------- segmented selective scan: LDS-staged rows, b128 reads + packed f32 math ----------------
// R17 structure; row reads widened to 10 aligned ds_read_b128 (6 for pass1), f2 operands
// extracted via shufflevector (register aliasing, no extra LDS ops).
template<int PASS>
__global__ __launch_bounds__(192)
void k_scan(const float* __restrict__ x1c, const float* __restrict__ x2c,
            const float* __restrict__ dbl,
            const float* __restrict__ dtw, const float* __restrict__ dtb,
            const float* __restrict__ alogs, const float* __restrict__ dsv,
            float* __restrict__ hend, float* __restrict__ dsum,
            const float* __restrict__ hin, float* __restrict__ merged) {
  __shared__ float sd[2][CHS * DBLS];   // 2 x 640 floats = 5120 B
  int bid = blockIdx.x;          // SS*BKT
  int s  = bid & (SS - 1);
  int bk = bid >> 7;             // 0..15
  int b = bk >> 2, kdir = bk & 3;
  int c = threadIdx.x;           // 0..191
  int kc = kdir * CI + c;

  float w2r0 = dtw[kc * RR + 0], w2r1 = dtw[kc * RR + 1], w2r2 = dtw[kc * RR + 2];
  float w2r3 = dtw[kc * RR + 3], w2r4 = dtw[kc * RR + 4], w2r5 = dtw[kc * RR + 5];
  float bias = dtb[kc];
  float Dv   = (PASS == 2) ? dsv[kc] : 0.f;
  float Areg[NN];
#pragma unroll
  for (int n = 0; n < NN; n++) Areg[n] = -__expf(alogs[kc * NN + n]);
  float A1 = Areg[0];
  int ok = 1;
#pragma unroll
  for (int n = 1; n < NN; n++) {
    float want = A1 * (float)(n + 1);
    if (!(fabsf(Areg[n] - want) <= fabsf(want) * 1e-3f + 1e-6f)) ok = 0;
  }
  const bool structured = (__all(ok) != 0);   // A[n] = (n+1)*A1 -> dA[n] = r^(n+1)

  f2 h2[8];
  if (PASS == 2) {
    const f2* hb = (const f2*)(hin + ((size_t)(s * BKT + bk) * CI + c) * NN);
#pragma unroll
    for (int j = 0; j < 8; j++) h2[j] = hb[j];
  } else {
#pragma unroll
    for (int j = 0; j < 8; j++) h2[j] = f2{0.f, 0.f};
  }
  float dacc = 0.f;

  const float* dpf = dbl + (size_t)(bk * L2T + s * TT) * DBLS;   // block-uniform segment base
  const float* u1b = x1c + (size_t)b * LL * CI + c;
  const float* u2b = x2c + (size_t)b * LL * CI + c;

  auto spmap = [&](int l) -> int {
    int lt = (kdir >= 2) ? (LL - 1 - l) : l;
    return (kdir & 1) ? (((lt & 63) << 6) | (lt >> 6)) : lt;
  };

  auto ldchunk = [&](int ch) -> float4 {
    if (threadIdx.x < 160)
      return *(const float4*)(dpf + ch * (CHS * DBLS) + threadIdx.x * 4);
    return float4{0.f, 0.f, 0.f, 0.f};
  };
  auto wrchunk = [&](int bufi, float4 v) {
    if (threadIdx.x < 160)
      *(float4*)&sd[bufi][threadIdx.x * 4] = v;
  };

  // one scan step; rowp = step's 40-float row in LDS. Reads: q0..q5 (pass1) / q0..q9 (pass2),
  // all 16B-aligned b128 broadcasts. f2 operands are register-aliased halves of the quads.
  auto step = [&](const float* rowp, float u, float& y) {
    const f4v* r4 = (const f4v*)rowp;
    f4v q0 = r4[0], q1 = r4[1], q2 = r4[2], q3 = r4[3], q4 = r4[4], q5 = r4[5];
    f4v q6 = {}, q7 = {}, q8 = {}, q9 = {};
    if (PASS == 2) { q6 = r4[6]; q7 = r4[7]; q8 = r4[8]; q9 = r4[9]; }
    float x = bias;
    x = fmaf(q0.x, w2r0, x); x = fmaf(q0.y, w2r1, x);
    x = fmaf(q0.z, w2r2, x); x = fmaf(q0.w, w2r3, x);
    x = fmaf(q1.x, w2r4, x); x = fmaf(q1.y, w2r5, x);
    float delta = (x > 15.f) ? x : __logf(1.f + __expf(x));
    float du = delta * u;
    f2 du2 = {du, du};
    // B pairs: floats (6,7)..(20,21); C pairs: floats (22,23)..(36,37)
    f2 B0 = HI2(q1), B1 = LO2(q2), B2_ = HI2(q2), B3 = LO2(q3);
    f2 B4 = HI2(q3), B5 = LO2(q4), B6 = HI2(q4), B7 = LO2(q5);
    f2 C0 = HI2(q5), C1 = LO2(q6), C2_ = HI2(q6), C3 = LO2(q7);
    f2 C4 = HI2(q7), C5 = LO2(q8), C6 = HI2(q8), C7 = LO2(q9);
    f2 y2a = {0.f, 0.f}, y2b = {0.f, 0.f};
    if (structured) {
      float r  = __expf(delta * A1);
      float r2 = r * r;
      f2 rr  = {r, r2};
      f2 r2v = {r2, r2};
      f2 r4v_ = r2v * r2v;
      f2 r8v = r4v_ * r4v_;
      f2 pw0 = rr;
      f2 pw1 = rr * r2v;
      f2 pw2 = rr * r4v_;
      f2 pw3 = pw1 * r4v_;
      f2 pw4 = rr * r8v;
      f2 pw5 = pw1 * r8v;
      f2 pw6 = pw2 * r8v;
      f2 pw7 = pw3 * r8v;
      h2[0] = fma2(h2[0], pw0, du2 * B0);
      h2[1] = fma2(h2[1], pw1, du2 * B1);
      h2[2] = fma2(h2[2], pw2, du2 * B2_);
      h2[3] = fma2(h2[3], pw3, du2 * B3);
      h2[4] = fma2(h2[4], pw4, du2 * B4);
      h2[5] = fma2(h2[5], pw5, du2 * B5);
      h2[6] = fma2(h2[6], pw6, du2 * B6);
      h2[7] = fma2(h2[7], pw7, du2 * B7);
      if (PASS == 2) {
        y2a = fma2(h2[0], C0, y2a); y2b = fma2(h2[1], C1, y2b);
        y2a = fma2(h2[2], C2_, y2a); y2b = fma2(h2[3], C3, y2b);
        y2a = fma2(h2[4], C4, y2a); y2b = fma2(h2[5], C5, y2b);
        y2a = fma2(h2[6], C6, y2a); y2b = fma2(h2[7], C7, y2b);
      }
    } else {
      f2 Bv[8] = {B0, B1, B2_, B3, B4, B5, B6, B7};
      f2 Cv[8] = {C0, C1, C2_, C3, C4, C5, C6, C7};
#pragma unroll
      for (int j = 0; j < 8; j++) {
        f2 dA2 = {__expf(delta * Areg[2 * j]), __expf(delta * Areg[2 * j + 1])};
        h2[j] = fma2(h2[j], dA2, du2 * Bv[j]);
        if (PASS == 2) {
          if (j & 1) y2b = fma2(h2[j], Cv[j], y2b);
          else       y2a = fma2(h2[j], Cv[j], y2a);
        }
      }
    }
    if (PASS == 1) dacc += delta;
    else {
      f2 ys = y2a + y2b;
      y = fmaf(u, Dv, ys.x + ys.y);
    }
  };

  const int NP = TT / 2;         // pairs
  int l0 = (s * TT) >> 1;
  int spC = spmap(l0);
  float u1C = u1b[(size_t)spC * CI];
  float u2C = u2b[(size_t)spC * CI];
  int spN = spmap(l0 + 1);
  float u1N = u1b[(size_t)spN * CI];
  float u2N = u2b[(size_t)spN * CI];
  int spN2 = spmap(l0 + 2);
  float u1N2 = u1b[(size_t)spN2 * CI];
  float u2N2 = u2b[(size_t)spN2 * CI];
  float4 stg = ldchunk(0);
  wrchunk(0, stg);
  stg = ldchunk(1);
  __syncthreads();

#pragma unroll 1
  for (int ch = 0; ch < NCH; ch++) {
    const float* cb = sd[ch & 1];
#pragma unroll 1
    for (int pp = 0; pp < CHS / 2; pp++) {
      int p = (ch * CHS) / 2 + pp;
      const float* rA = &cb[(pp * 2) * DBLS];
      const float* rB = &cb[(pp * 2 + 1) * DBLS];
      int spN3 = 0; float u1N3 = 0.f, u2N3 = 0.f;
      if (p + 3 < NP) {
        spN3 = spmap(l0 + p + 3);
        u1N3 = u1b[(size_t)spN3 * CI];
        u2N3 = u2b[(size_t)spN3 * CI];
      }
      float ya, yb;
      step(rA, u1C, ya);                      // even step: modality rgb (m=0)
      step(rB, u2C, yb);                      // odd step: modality t (m=1)
      if (PASS == 2) {
        float* mrow = merged + (size_t)(b * LL + spC) * (2 * CI) + c;
        atomicAdd(mrow, ya);
        atomicAdd(mrow + CI, yb);
      }
      spC = spN;  u1C = u1N;  u2C = u2N;
      spN = spN2; u1N = u1N2; u2N = u2N2;
      spN2 = spN3; u1N2 = u1N3; u2N2 = u2N3;
    }
    if (ch + 1 < NCH) {
      wrchunk((ch + 1) & 1, stg);             // barrier-protected overwrite
      if (ch + 2 < NCH) stg = ldchunk(ch + 2);
      __syncthreads();
    }
  }

  if (PASS == 1) {
    f2* hb = (f2*)(hend + ((size_t)(s * BKT + bk) * CI + c) * NN);
#pragma unroll
    for (int j = 0; j < 8; j++) hb[j] = h2[j];
    dsum[(s * BKT + bk) * CI + c] = dacc;
  }
}

// ---------------- propagate segment initial states (two-buffer) ----------------
__global__ __launch_bounds__(256)
void k_prop(const float* __restrict__ hend, const float* __restrict__ dsum,
            const float* __restrict__ alogs, float* __restrict__ hin) {
  int idx = blockIdx.x * 256 + threadIdx.x;   // BKT*CI*NN = 49152
  int n = idx & 15;
  int rest = idx >> 4;
  int c = rest % CI;
  int bk = rest / CI;
  int k = bk & 3;
  float A = -__expf(alogs[(k * CI + c) * NN + n]);
  float h = 0.f;
  for (int s = 0; s < SS; s++) {
    int cell = (s * BKT + bk) * CI + c;
    hin[cell * NN + n] = h;
    float ap = __expf(A * dsum[cell]);
    h = h * ap + hend[cell * NN + n];
  }
}

// ---------------- out_proj FUSED with LayerNorm + SiLU(z) gate (R17, unchanged) ----------------
__global__ __launch_bounds__(256)
void k_outproj(const float* __restrict__ g,
               const float* __restrict__ z1, const float* __restrict__ z2,
               const float* __restrict__ n1w, const float* __restrict__ n1b,
               const float* __restrict__ n2w, const float* __restrict__ n2b,
               const float* __restrict__ w1, const float* __restrict__ w2,
               float* __restrict__ out) {
  int mb = blockIdx.x;
  int m  = blockIdx.y;
  const float* w = m ? w2 : w1;
  const float* nw = m ? n2w : n1w;
  const float* nb = m ? n2b : n1b;
  const float* zz = m ? z2 : z1;
  __shared__ float As[64][100];
  __shared__ float Ws[96][98];
  __shared__ float st[64][2];    // mean, rstd per row
  int t = threadIdx.x;

  // Phase A: row statistics
  {
    int r = t >> 2, q = t & 3;
    const float4* grow = (const float4*)(g + ((size_t)(mb * 64 + r) * 2 + m) * CI + q * 48);
    float s1 = 0.f, s2 = 0.f;
#pragma unroll
    for (int i = 0; i < 12; i++) {
      float4 v = grow[i];
      s1 += (v.x + v.y) + (v.z + v.w);
      s2 += (v.x * v.x + v.y * v.y) + (v.z * v.z + v.w * v.w);
    }
    s1 += __shfl_xor(s1, 1); s2 += __shfl_xor(s2, 1);
    s1 += __shfl_xor(s1, 2); s2 += __shfl_xor(s2, 2);
    if (q == 0) {
      float mean = s1 * (1.f / CI);
      float var = s2 * (1.f / CI) - mean * mean;
      st[r][0] = mean;
      st[r][1] = rsqrtf(var + 1e-5f);
    }
  }
  __syncthreads();

  int tc = t & 15, tr = t >> 4;
  float acc[4][6] = {};
  for (int kc = 0; kc < 2; kc++) {
    if (kc) __syncthreads();
    for (int i = t; i < 1536; i += 256) {
      int r = i / 24, kk = (i % 24) * 4;
      int cc = kc * 96 + kk;
      float4 gv = *(const float4*)&g[((size_t)(mb * 64 + r) * 2 + m) * CI + cc];
      float4 zv = *(const float4*)&zz[(size_t)(mb * 64 + r) * CI + cc];
      float4 wv = *(const float4*)&nw[cc];
      float4 bv = *(const float4*)&nb[cc];
      float mean = st[r][0], rstd = st[r][1];
      float4 o;
      o.x = ((gv.x - mean) * rstd * wv.x + bv.x) * (zv.x / (1.f + __expf(-zv.x)));
      o.y = ((gv.y - mean) * rstd * wv.y + bv.y) * (zv.y / (1.f + __expf(-zv.y)));
      o.z = ((gv.z - mean) * rstd * wv.z + bv.z) * (zv.z / (1.f + __expf(-zv.z)));
      o.w = ((gv.w - mean) * rstd * wv.w + bv.w) * (zv.w / (1.f + __expf(-zv.w)));
      *(float4*)&As[r][kk] = o;
    }
    for (int i = t; i < 4608; i += 256) {
      int r = i / 48, kk = (i % 48) * 2;
      *(float2*)&Ws[r][kk] = *(const float2*)&w[(size_t)r * CI + kc * 96 + kk];
    }
    __syncthreads();
    for (int k = 0; k < 96; k += 2) {
      float2 a[4], b[6];
#pragma unroll
      for (int i = 0; i < 4; i++) a[i] = *(const float2*)&As[tr * 4 + i][k];
#pragma unroll
      for (int j = 0; j < 6; j++) b[j] = *(const float2*)&Ws[tc * 6 + j][k];
#pragma unroll
      for (int i = 0; i < 4; i++)
#pragma unroll
        for (int j = 0; j < 6; j++) {
          acc[i][j] = fmaf(a[i].x, b[j].x, acc[i][j]);
          acc[i][j] = fmaf(a[i].y, b[j].y, acc[i][j]);
        }
    }
  }
  float* outp = out + (size_t)m * (BB * LL * DM);
#pragma unroll
  for (int i = 0; i < 4; i++) {
    size_t bl = (size_t)mb * 64 + tr * 4 + i;
#pragma unroll
    for (int j = 0; j < 6; j++)
      outp[bl * DM + tc * 6 + j] = acc[i][j];
  }
}

extern "C" void kernel_launch(void* const* d_in, const int* in_sizes, int n_in,
                              void* d_out, int out_size, void* d_ws, size_t ws_size,
                              hipStream_t stream) {
  const float* rgb = (const float*)d_in[0];
  const float* tin = (const float*)d_in[1];
  const float* ip1 = (const float*)d_in[2];
  const float* ip2 = (const float*)d_in[3];
  const float* c1w = (const float*)d_in[4];
  const float* c1b = (const float*)d_in[5];
  const float* c2w = (const float*)d_in[6];
  const float* c2b = (const float*)d_in[7];
  const float* wx  = (const float*)d_in[8];
  const float* dtw = (const float*)d_in[9];
  const float* dtb = (const float*)d_in[10];
  const float* alg = (const float*)d_in[11];
  const float* Dsp = (const float*)d_in[12];
  const float* n1w = (const float*)d_in[13];
  const float* n1b = (const float*)d_in[14];
  const float* n2w = (const float*)d_in[15];
  const float* n2b = (const float*)d_in[16];
  const float* op1 = (const float*)d_in[17];
  const float* op2 = (const float*)d_in[18];

  float* ws = (float*)d_ws;
  float* xp1 = ws + OFF_XPRE1;
  float* xp2 = ws + OFF_XPRE2;
  float* z1  = ws + OFF_Z1;
  float* z2  = ws + OFF_Z2;
  float* x1c = ws + OFF_X1C;
  float* x2c = ws + OFF_X2C;
  float* dbl = ws + OFF_DBL;
  float* mg  = ws + OFF_MERG;
  float* dsm = ws + OFF_DSUM;
  // hend lives in the mg region (pass1 -> prop only; memset erases it afterwards).
  // hin spans xp1+xp2 (dead after k_conv): SS*BKT*CI*NN = 6291456 floats, exact fit.
  float* he  = ws + OFF_MERG;
  float* hi  = ws + OFF_XPRE1;
  float* out = (float*)d_out;

  k_inproj<<<dim3(256, 4, 2), 256, 0, stream>>>(rgb, tin, ip1, ip2, xp1, xp2, z1, z2);
  k_conv<<<dim3(12288, 2), 256, 0, stream>>>(xp1, xp2, c1w, c1b, c2w, c2b, x1c, x2c);
  k_dbl<<<dim3(128, 16), 256, 0, stream>>>(x1c, x2c, wx, dbl);
  k_scan<1><<<SS * BKT, 192, 0, stream>>>(x1c, x2c, dbl, dtw, dtb, alg, Dsp, he, dsm, hi, mg);
  k_prop<<<192, 256, 0, stream>>>(he, dsm, alg, hi);
  // zero the merge accumulator only now (hend is dead after k_prop)
  hipMemsetAsync(mg, 0, (size_t)6291456 * sizeof(float), stream);
  k_scan<2><<<SS * BKT, 192, 0, stream>>>(x1c, x2c, dbl, dtw, dtb, alg, Dsp, he, dsm, hi, mg);
  k_outproj<<<dim3(256, 2), 256, 0, stream>>>(mg, z1, z2, n1w, n1b, n2w, n2b, op1, op2, out);
}

// Round 19
// 390.745 us; speedup vs baseline: 1.1406x; 1.0081x over previous
//
#include <hip/hip_runtime.h>
#include <math.h>

// Problem constants
#define BB   4
#define LL   4096          // H*W
#define L2T  8192          // 2*L (modality-interleaved sequence)
#define DM   96            // D_MODEL
#define CI   192           // D_INNER
#define KD   4             // K directions
#define NN   16            // D_STATE
#define RR   6             // DT_RANK
#define BKT  16            // B*K
#define SS   128           // scan segments
#define TT   64            // steps per segment = L2T/SS
#define DBLS 40            // padded row stride for x_dbl (38 -> 40 for float4)
#define CHS  16            // steps per LDS-staged chunk
#define NCH  (TT / CHS)    // 4 chunks per segment

// Workspace layout (float offsets) — identical to R9..R18 (proven)
#define OFF_XPRE1 0
#define OFF_XPRE2 3145728
#define OFF_Z1    6291456
#define OFF_Z2    9437184
#define OFF_X1C   12582912
#define OFF_X2C   15728640
#define OFF_DBL   18874368   // BKT*L2T*40 = 5242880
#define OFF_MERG  24117248   // B*L*2*CI = 6291456 == SS*BKT*CI*NN (hend fits exactly)
#define OFF_DSUM  30408704   // SS*BKT*CI = 393216

typedef float f2 __attribute__((ext_vector_type(2)));
typedef float f4v __attribute__((ext_vector_type(4)));
static __device__ __forceinline__ f2 fma2(f2 a, f2 b, f2 c) {
  return __builtin_elementwise_fma(a, b, c);
}
#define LO2(q) __builtin_shufflevector(q, q, 0, 1)
#define HI2(q) __builtin_shufflevector(q, q, 2, 3)

// ---------------- in_proj: LDS-tiled GEMM. M=16384, N=384 (4 tiles of 96), K=96 ----------------
__global__ __launch_bounds__(256)
void k_inproj(const float* __restrict__ rgb, const float* __restrict__ tin,
              const float* __restrict__ w1, const float* __restrict__ w2,
              float* __restrict__ xp1, float* __restrict__ xp2,
              float* __restrict__ zz1, float* __restrict__ zz2) {
  int mb = blockIdx.x;     // row tile
  int nb = blockIdx.y;     // col tile (0..3)
  int m  = blockIdx.z;     // modality
  const float* in = m ? tin : rgb;
  const float* w  = (m ? w2 : w1) + nb * 96 * DM;
  __shared__ float As[64][100];
  __shared__ float Ws[96][98];
  int t = threadIdx.x;
  const float4* asrc = (const float4*)(in + (size_t)mb * 64 * DM);
  for (int i = t; i < 1536; i += 256) {
    int r = i / 24, kk = (i % 24) * 4;
    *(float4*)&As[r][kk] = asrc[i];
  }
  const float2* wsrc = (const float2*)w;
  for (int i = t; i < 4608; i += 256) {
    int r = i / 48, kk = (i % 48) * 2;
    *(float2*)&Ws[r][kk] = wsrc[i];
  }
  __syncthreads();
  int tc = t & 15, tr = t >> 4;
  float acc[4][6] = {};
  for (int k = 0; k < 96; k += 2) {
    float2 a[4], b[6];
#pragma unroll
    for (int i = 0; i < 4; i++) a[i] = *(const float2*)&As[tr * 4 + i][k];
#pragma unroll
    for (int j = 0; j < 6; j++) b[j] = *(const float2*)&Ws[tc * 6 + j][k];
#pragma unroll
    for (int i = 0; i < 4; i++)
#pragma unroll
      for (int j = 0; j < 6; j++) {
        acc[i][j] = fmaf(a[i].x, b[j].x, acc[i][j]);
        acc[i][j] = fmaf(a[i].y, b[j].y, acc[i][j]);
      }
  }
  float* dst = (nb < 2) ? (m ? xp2 : xp1) : (m ? zz2 : zz1);
  int colbase = (nb & 1) * 96 + tc * 6;
#pragma unroll
  for (int i = 0; i < 4; i++) {
    size_t bl = (size_t)mb * 64 + tr * 4 + i;
#pragma unroll
    for (int j = 0; j < 6; j++)
      dst[bl * CI + colbase + j] = acc[i][j];
  }
}

// ---------------- depthwise 3x3 conv (SAME, zero pad) + bias + SiLU ----------------
__global__ __launch_bounds__(256)
void k_conv(const float* __restrict__ xp1, const float* __restrict__ xp2,
            const float* __restrict__ c1w, const float* __restrict__ c1b,
            const float* __restrict__ c2w, const float* __restrict__ c2b,
            float* __restrict__ o1, float* __restrict__ o2) {
  int m = blockIdx.y;
  const float* in = m ? xp2 : xp1;
  const float* cw = m ? c2w : c1w;
  const float* cb = m ? c2b : c1b;
  float* out = m ? o2 : o1;
  int idx = blockIdx.x * 256 + threadIdx.x;
  int c = idx % CI;
  int bl = idx / CI;
  int b = bl / LL, l = bl % LL;
  int hh = l >> 6, ww = l & 63;
  float a = cb[c];
#pragma unroll
  for (int di = 0; di < 3; di++) {
    int h2 = hh + di - 1;
    if ((unsigned)h2 >= 64u) continue;
#pragma unroll
    for (int dj = 0; dj < 3; dj++) {
      int w2 = ww + dj - 1;
      if ((unsigned)w2 >= 64u) continue;
      a = fmaf(in[(b * LL + h2 * 64 + w2) * CI + c], cw[c * 9 + di * 3 + dj], a);
    }
  }
  out[idx] = a / (1.f + __expf(-a));
}

// ---------------- x_dbl projection as tiled GEMM per (b,k) ----------------
__global__ __launch_bounds__(256)
void k_dbl(const float* __restrict__ x1c, const float* __restrict__ x2c,
           const float* __restrict__ wx, float* __restrict__ dbl) {
  int pt = blockIdx.x;
  int bk = blockIdx.y;
  int b = bk >> 2, k = bk & 3;
  __shared__ float As[64][100];
  __shared__ float Ws[40][100];
  int t = threadIdx.x;
  int tc = t & 7, tr = t >> 3;
  float acc[2][5] = {};
  for (int kc = 0; kc < 2; kc++) {
    if (kc) __syncthreads();
    for (int i = t; i < 1536; i += 256) {
      int r = i / 24, kk = (i % 24) * 4;
      int l2 = pt * 64 + r;
      int mm = l2 & 1, l = l2 >> 1;
      int lt = (k >= 2) ? (LL - 1 - l) : l;
      int sp = (k & 1) ? (((lt & 63) << 6) | (lt >> 6)) : lt;
      const float* src = (mm ? x2c : x1c) + ((size_t)(b * LL + sp)) * CI + kc * 96;
      *(float4*)&As[r][kk] = *(const float4*)(src + kk);
    }
    for (int i = t; i < 960; i += 256) {
      int r = i / 24, kk = (i % 24) * 4;
      float4 v;
      if (r < 38) v = *(const float4*)&wx[(size_t)(k * 38 + r) * CI + kc * 96 + kk];
      else        v = float4{0.f, 0.f, 0.f, 0.f};
      *(float4*)&Ws[r][kk] = v;
    }
    __syncthreads();
    for (int kk2 = 0; kk2 < 96; kk2 += 2) {
      float2 a[2], bv[5];
#pragma unroll
      for (int i = 0; i < 2; i++) a[i] = *(const float2*)&As[tr * 2 + i][kk2];
#pragma unroll
      for (int j = 0; j < 5; j++) bv[j] = *(const float2*)&Ws[tc * 5 + j][kk2];
#pragma unroll
      for (int i = 0; i < 2; i++)
#pragma unroll
        for (int j = 0; j < 5; j++) {
          acc[i][j] = fmaf(a[i].x, bv[j].x, acc[i][j]);
          acc[i][j] = fmaf(a[i].y, bv[j].y, acc[i][j]);
        }
    }
  }
#pragma unroll
  for (int i = 0; i < 2; i++) {
    size_t row = (size_t)bk * L2T + pt * 64 + tr * 2 + i;
#pragma unroll
    for (int j = 0; j < 5; j++) {
      int cc = tc * 5 + j;
      if (cc < 38) dbl[row * DBLS + cc] = acc[i][j];
    }
  }
}

// ---------------- segmented selective scan: LDS-staged rows, b128 reads, packed math ----------------
// R18 + A1==-1 fast path: r = e^{-delta} = rcp(1+e^x) computed directly from e^x, so the
// softplus log moves OFF the critical chain (delta only feeds du/dacc). Guarded by the
// wave-uniform `structured` check (now also requires A1 == -1 within 1e-3).
template<int PASS>
__global__ __launch_bounds__(192)
void k_scan(const float* __restrict__ x1c, const float* __restrict__ x2c,
            const float* __restrict__ dbl,
            const float* __restrict__ dtw, const float* __restrict__ dtb,
            const float* __restrict__ alogs, const float* __restrict__ dsv,
            float* __restrict__ hend, float* __restrict__ dsum,
            const float* __restrict__ hin, float* __restrict__ merged) {
  __shared__ float sd[2][CHS * DBLS];   // 2 x 640 floats = 5120 B
  int bid = blockIdx.x;          // SS*BKT
  int s  = bid & (SS - 1);
  int bk = bid >> 7;             // 0..15
  int b = bk >> 2, kdir = bk & 3;
  int c = threadIdx.x;           // 0..191
  int kc = kdir * CI + c;

  float w2r0 = dtw[kc * RR + 0], w2r1 = dtw[kc * RR + 1], w2r2 = dtw[kc * RR + 2];
  float w2r3 = dtw[kc * RR + 3], w2r4 = dtw[kc * RR + 4], w2r5 = dtw[kc * RR + 5];
  float bias = dtb[kc];
  float Dv   = (PASS == 2) ? dsv[kc] : 0.f;
  float Areg[NN];
#pragma unroll
  for (int n = 0; n < NN; n++) Areg[n] = -__expf(alogs[kc * NN + n]);
  float A1 = Areg[0];
  int ok = (fabsf(A1 + 1.f) <= 1e-3f) ? 1 : 0;   // fast path also needs A1 == -1
#pragma unroll
  for (int n = 1; n < NN; n++) {
    float want = A1 * (float)(n + 1);
    if (!(fabsf(Areg[n] - want) <= fabsf(want) * 1e-3f + 1e-6f)) ok = 0;
  }
  const bool structured = (__all(ok) != 0);   // A[n] = -(n+1) -> dA[n] = r^(n+1), r = e^{-delta}

  f2 h2[8];
  if (PASS == 2) {
    const f2* hb = (const f2*)(hin + ((size_t)(s * BKT + bk) * CI + c) * NN);
#pragma unroll
    for (int j = 0; j < 8; j++) h2[j] = hb[j];
  } else {
#pragma unroll
    for (int j = 0; j < 8; j++) h2[j] = f2{0.f, 0.f};
  }
  float dacc = 0.f;

  const float* dpf = dbl + (size_t)(bk * L2T + s * TT) * DBLS;   // block-uniform segment base
  const float* u1b = x1c + (size_t)b * LL * CI + c;
  const float* u2b = x2c + (size_t)b * LL * CI + c;

  auto spmap = [&](int l) -> int {
    int lt = (kdir >= 2) ? (LL - 1 - l) : l;
    return (kdir & 1) ? (((lt & 63) << 6) | (lt >> 6)) : lt;
  };

  auto ldchunk = [&](int ch) -> float4 {
    if (threadIdx.x < 160)
      return *(const float4*)(dpf + ch * (CHS * DBLS) + threadIdx.x * 4);
    return float4{0.f, 0.f, 0.f, 0.f};
  };
  auto wrchunk = [&](int bufi, float4 v) {
    if (threadIdx.x < 160)
      *(float4*)&sd[bufi][threadIdx.x * 4] = v;
  };

  auto step = [&](const float* rowp, float u, float& y) {
    const f4v* r4 = (const f4v*)rowp;
    f4v q0 = r4[0], q1 = r4[1], q2 = r4[2], q3 = r4[3], q4 = r4[4], q5 = r4[5];
    f4v q6 = {}, q7 = {}, q8 = {}, q9 = {};
    if (PASS == 2) { q6 = r4[6]; q7 = r4[7]; q8 = r4[8]; q9 = r4[9]; }
    float x = bias;
    x = fmaf(q0.x, w2r0, x); x = fmaf(q0.y, w2r1, x);
    x = fmaf(q0.z, w2r2, x); x = fmaf(q0.w, w2r3, x);
    x = fmaf(q1.x, w2r4, x); x = fmaf(q1.y, w2r5, x);
    // B pairs: floats (6,7)..(20,21); C pairs: floats (22,23)..(36,37)
    f2 B0 = HI2(q1), B1 = LO2(q2), B2_ = HI2(q2), B3 = LO2(q3);
    f2 B4 = HI2(q3), B5 = LO2(q4), B6 = HI2(q4), B7 = LO2(q5);
    f2 C0 = HI2(q5), C1 = LO2(q6), C2_ = HI2(q6), C3 = LO2(q7);
    f2 C4 = HI2(q7), C5 = LO2(q8), C6 = HI2(q8), C7 = LO2(q9);
    f2 y2a = {0.f, 0.f}, y2b = {0.f, 0.f};
    if (structured) {
      // r = e^{-delta} = 1/(1+e^x); delta = log(1+e^x) (off critical path, feeds du only)
      float t = __expf(x);
      float den = 1.f + t;
      float r = __builtin_amdgcn_rcpf(den);        // x large -> den=inf -> r=0 (correct decay)
      float delta = (x > 15.f) ? x : __logf(den);
      float du = delta * u;
      f2 du2 = {du, du};
      float r2 = r * r;
      f2 rr  = {r, r2};
      f2 r2v = {r2, r2};
      f2 r4v_ = r2v * r2v;
      f2 r8v = r4v_ * r4v_;
      f2 pw0 = rr;
      f2 pw1 = rr * r2v;
      f2 pw2 = rr * r4v_;
      f2 pw3 = pw1 * r4v_;
      f2 pw4 = rr * r8v;
      f2 pw5 = pw1 * r8v;
      f2 pw6 = pw2 * r8v;
      f2 pw7 = pw3 * r8v;
      h2[0] = fma2(h2[0], pw0, du2 * B0);
      h2[1] = fma2(h2[1], pw1, du2 * B1);
      h2[2] = fma2(h2[2], pw2, du2 * B2_);
      h2[3] = fma2(h2[3], pw3, du2 * B3);
      h2[4] = fma2(h2[4], pw4, du2 * B4);
      h2[5] = fma2(h2[5], pw5, du2 * B5);
      h2[6] = fma2(h2[6], pw6, du2 * B6);
      h2[7] = fma2(h2[7], pw7, du2 * B7);
      if (PASS == 2) {
        y2a = fma2(h2[0], C0, y2a); y2b = fma2(h2[1], C1, y2b);
        y2a = fma2(h2[2], C2_, y2a); y2b = fma2(h2[3], C3, y2b);
        y2a = fma2(h2[4], C4, y2a); y2b = fma2(h2[5], C5, y2b);
        y2a = fma2(h2[6], C6, y2a); y2b = fma2(h2[7], C7, y2b);
      }
      if (PASS == 1) dacc += delta;
      else {
        f2 ys = y2a + y2b;
        y = fmaf(u, Dv, ys.x + ys.y);
      }
    } else {
      float delta = (x > 15.f) ? x : __logf(1.f + __expf(x));
      float du = delta * u;
      f2 du2 = {du, du};
      f2 Bv[8] = {B0, B1, B2_, B3, B4, B5, B6, B7};
      f2 Cv[8] = {C0, C1, C2_, C3, C4, C5, C6, C7};
#pragma unroll
      for (int j = 0; j < 8; j++) {
        f2 dA2 = {__expf(delta * Areg[2 * j]), __expf(delta * Areg[2 * j + 1])};
        h2[j] = fma2(h2[j], dA2, du2 * Bv[j]);
        if (PASS == 2) {
          if (j & 1) y2b = fma2(h2[j], Cv[j], y2b);
          else       y2a = fma2(h2[j], Cv[j], y2a);
        }
      }
      if (PASS == 1) dacc += delta;
      else {
        f2 ys = y2a + y2b;
        y = fmaf(u, Dv, ys.x + ys.y);
      }
    }
  };

  const int NP = TT / 2;         // pairs
  int l0 = (s * TT) >> 1;
  int spC = spmap(l0);
  float u1C = u1b[(size_t)spC * CI];
  float u2C = u2b[(size_t)spC * CI];
  int spN = spmap(l0 + 1);
  float u1N = u1b[(size_t)spN * CI];
  float u2N = u2b[(size_t)spN * CI];
  int spN2 = spmap(l0 + 2);
  float u1N2 = u1b[(size_t)spN2 * CI];
  float u2N2 = u2b[(size_t)spN2 * CI];
  float4 stg = ldchunk(0);
  wrchunk(0, stg);
  stg = ldchunk(1);
  __syncthreads();

#pragma unroll 1
  for (int ch = 0; ch < NCH; ch++) {
    const float* cb = sd[ch & 1];
#pragma unroll 1
    for (int pp = 0; pp < CHS / 2; pp++) {
      int p = (ch * CHS) / 2 + pp;
      const float* rA = &cb[(pp * 2) * DBLS];
      const float* rB = &cb[(pp * 2 + 1) * DBLS];
      int spN3 = 0; float u1N3 = 0.f, u2N3 = 0.f;
      if (p + 3 < NP) {
        spN3 = spmap(l0 + p + 3);
        u1N3 = u1b[(size_t)spN3 * CI];
        u2N3 = u2b[(size_t)spN3 * CI];
      }
      float ya, yb;
      step(rA, u1C, ya);                      // even step: modality rgb (m=0)
      step(rB, u2C, yb);                      // odd step: modality t (m=1)
      if (PASS == 2) {
        float* mrow = merged + (size_t)(b * LL + spC) * (2 * CI) + c;
        atomicAdd(mrow, ya);
        atomicAdd(mrow + CI, yb);
      }
      spC = spN;  u1C = u1N;  u2C = u2N;
      spN = spN2; u1N = u1N2; u2N = u2N2;
      spN2 = spN3; u1N2 = u1N3; u2N2 = u2N3;
    }
    if (ch + 1 < NCH) {
      wrchunk((ch + 1) & 1, stg);             // barrier-protected overwrite
      if (ch + 2 < NCH) stg = ldchunk(ch + 2);
      __syncthreads();
    }
  }

  if (PASS == 1) {
    f2* hb = (f2*)(hend + ((size_t)(s * BKT + bk) * CI + c) * NN);
#pragma unroll
    for (int j = 0; j < 8; j++) hb[j] = h2[j];
    dsum[(s * BKT + bk) * CI + c] = dacc;
  }
}

// ---------------- propagate segment initial states (two-buffer) ----------------
__global__ __launch_bounds__(256)
void k_prop(const float* __restrict__ hend, const float* __restrict__ dsum,
            const float* __restrict__ alogs, float* __restrict__ hin) {
  int idx = blockIdx.x * 256 + threadIdx.x;   // BKT*CI*NN = 49152
  int n = idx & 15;
  int rest = idx >> 4;
  int c = rest % CI;
  int bk = rest / CI;
  int k = bk & 3;
  float A = -__expf(alogs[(k * CI + c) * NN + n]);
  float h = 0.f;
  for (int s = 0; s < SS; s++) {
    int cell = (s * BKT + bk) * CI + c;
    hin[cell * NN + n] = h;
    float ap = __expf(A * dsum[cell]);
    h = h * ap + hend[cell * NN + n];
  }
}

// ---------------- out_proj FUSED with LayerNorm + SiLU(z) gate (R17, unchanged) ----------------
__global__ __launch_bounds__(256)
void k_outproj(const float* __restrict__ g,
               const float* __restrict__ z1, const float* __restrict__ z2,
               const float* __restrict__ n1w, const float* __restrict__ n1b,
               const float* __restrict__ n2w, const float* __restrict__ n2b,
               const float* __restrict__ w1, const float* __restrict__ w2,
               float* __restrict__ out) {
  int mb = blockIdx.x;
  int m  = blockIdx.y;
  const float* w = m ? w2 : w1;
  const float* nw = m ? n2w : n1w;
  const float* nb = m ? n2b : n1b;
  const float* zz = m ? z2 : z1;
  __shared__ float As[64][100];
  __shared__ float Ws[96][98];
  __shared__ float st[64][2];    // mean, rstd per row
  int t = threadIdx.x;

  // Phase A: row statistics
  {
    int r = t >> 2, q = t & 3;
    const float4* grow = (const float4*)(g + ((size_t)(mb * 64 + r) * 2 + m) * CI + q * 48);
    float s1 = 0.f, s2 = 0.f;
#pragma unroll
    for (int i = 0; i < 12; i++) {
      float4 v = grow[i];
      s1 += (v.x + v.y) + (v.z + v.w);
      s2 += (v.x * v.x + v.y * v.y) + (v.z * v.z + v.w * v.w);
    }
    s1 += __shfl_xor(s1, 1); s2 += __shfl_xor(s2, 1);
    s1 += __shfl_xor(s1, 2); s2 += __shfl_xor(s2, 2);
    if (q == 0) {
      float mean = s1 * (1.f / CI);
      float var = s2 * (1.f / CI) - mean * mean;
      st[r][0] = mean;
      st[r][1] = rsqrtf(var + 1e-5f);
    }
  }
  __syncthreads();

  int tc = t & 15, tr = t >> 4;
  float acc[4][6] = {};
  for (int kc = 0; kc < 2; kc++) {
    if (kc) __syncthreads();
    for (int i = t; i < 1536; i += 256) {
      int r = i / 24, kk = (i % 24) * 4;
      int cc = kc * 96 + kk;
      float4 gv = *(const float4*)&g[((size_t)(mb * 64 + r) * 2 + m) * CI + cc];
      float4 zv = *(const float4*)&zz[(size_t)(mb * 64 + r) * CI + cc];
      float4 wv = *(const float4*)&nw[cc];
      float4 bv = *(const float4*)&nb[cc];
      float mean = st[r][0], rstd = st[r][1];
      float4 o;
      o.x = ((gv.x - mean) * rstd * wv.x + bv.x) * (zv.x / (1.f + __expf(-zv.x)));
      o.y = ((gv.y - mean) * rstd * wv.y + bv.y) * (zv.y / (1.f + __expf(-zv.y)));
      o.z = ((gv.z - mean) * rstd * wv.z + bv.z) * (zv.z / (1.f + __expf(-zv.z)));
      o.w = ((gv.w - mean) * rstd * wv.w + bv.w) * (zv.w / (1.f + __expf(-zv.w)));
      *(float4*)&As[r][kk] = o;
    }
    for (int i = t; i < 4608; i += 256) {
      int r = i / 48, kk = (i % 48) * 2;
      *(float2*)&Ws[r][kk] = *(const float2*)&w[(size_t)r * CI + kc * 96 + kk];
    }
    __syncthreads();
    for (int k = 0; k < 96; k += 2) {
      float2 a[4], b[6];
#pragma unroll
      for (int i = 0; i < 4; i++) a[i] = *(const float2*)&As[tr * 4 + i][k];
#pragma unroll
      for (int j = 0; j < 6; j++) b[j] = *(const float2*)&Ws[tc * 6 + j][k];
#pragma unroll
      for (int i = 0; i < 4; i++)
#pragma unroll
        for (int j = 0; j < 6; j++) {
          acc[i][j] = fmaf(a[i].x, b[j].x, acc[i][j]);
          acc[i][j] = fmaf(a[i].y, b[j].y, acc[i][j]);
        }
    }
  }
  float* outp = out + (size_t)m * (BB * LL * DM);
#pragma unroll
  for (int i = 0; i < 4; i++) {
    size_t bl = (size_t)mb * 64 + tr * 4 + i;
#pragma unroll
    for (int j = 0; j < 6; j++)
      outp[bl * DM + tc * 6 + j] = acc[i][j];
  }
}

extern "C" void kernel_launch(void* const* d_in, const int* in_sizes, int n_in,
                              void* d_out, int out_size, void* d_ws, size_t ws_size,
                              hipStream_t stream) {
  const float* rgb = (const float*)d_in[0];
  const float* tin = (const float*)d_in[1];
  const float* ip1 = (const float*)d_in[2];
  const float* ip2 = (const float*)d_in[3];
  const float* c1w = (const float*)d_in[4];
  const float* c1b = (const float*)d_in[5];
  const float* c2w = (const float*)d_in[6];
  const float* c2b = (const float*)d_in[7];
  const float* wx  = (const float*)d_in[8];
  const float* dtw = (const float*)d_in[9];
  const float* dtb = (const float*)d_in[10];
  const float* alg = (const float*)d_in[11];
  const float* Dsp = (const float*)d_in[12];
  const float* n1w = (const float*)d_in[13];
  const float* n1b = (const float*)d_in[14];
  const float* n2w = (const float*)d_in[15];
  const float* n2b = (const float*)d_in[16];
  const float* op1 = (const float*)d_in[17];
  const float* op2 = (const float*)d_in[18];

  float* ws = (float*)d_ws;
  float* xp1 = ws + OFF_XPRE1;
  float* xp2 = ws + OFF_XPRE2;
  float* z1  = ws + OFF_Z1;
  float* z2  = ws + OFF_Z2;
  float* x1c = ws + OFF_X1C;
  float* x2c = ws + OFF_X2C;
  float* dbl = ws + OFF_DBL;
  float* mg  = ws + OFF_MERG;
  float* dsm = ws + OFF_DSUM;
  // hend lives in the mg region (pass1 -> prop only; memset erases it afterwards).
  // hin spans xp1+xp2 (dead after k_conv): SS*BKT*CI*NN = 6291456 floats, exact fit.
  float* he  = ws + OFF_MERG;
  float* hi  = ws + OFF_XPRE1;
  float* out = (float*)d_out;

  k_inproj<<<dim3(256, 4, 2), 256, 0, stream>>>(rgb, tin, ip1, ip2, xp1, xp2, z1, z2);
  k_conv<<<dim3(12288, 2), 256, 0, stream>>>(xp1, xp2, c1w, c1b, c2w, c2b, x1c, x2c);
  k_dbl<<<dim3(128, 16), 256, 0, stream>>>(x1c, x2c, wx, dbl);
  k_scan<1><<<SS * BKT, 192, 0, stream>>>(x1c, x2c, dbl, dtw, dtb, alg, Dsp, he, dsm, hi, mg);
  k_prop<<<192, 256, 0, stream>>>(he, dsm, alg, hi);
  // zero the merge accumulator only now (hend is dead after k_prop)
  hipMemsetAsync(mg, 0, (size_t)6291456 * sizeof(float), stream);
  k_scan<2><<<SS * BKT, 192, 0, stream>>>(x1c, x2c, dbl, dtw, dtb, alg, Dsp, he, dsm, hi, mg);
  k_outproj<<<dim3(256, 2), 256, 0, stream>>>(mg, z1, z2, n1w, n1b, n2w, n2b, op1, op2, out);
}